// Round 2
// baseline (343.361 us; speedup 1.0000x reference)
//
#include <hip/hip_runtime.h>
#include <stdint.h>

typedef unsigned short u16;
typedef unsigned long long u64;
using f32x4 = __attribute__((ext_vector_type(4))) float;
using s16x8 = __attribute__((ext_vector_type(8))) short;
using u16x4 = __attribute__((ext_vector_type(4))) unsigned short;

static constexpr float kScale = 0.08838834764831845f;              // 128^-0.5
static constexpr float kQScale = (float)(0.08838834764831845 * 1.4426950408889634);  // SCALE*log2(e)

__device__ __forceinline__ u16 f2bf(float f) {
  uint32_t u = __float_as_uint(f);
  u += 0x7fffu + ((u >> 16) & 1u);   // RNE
  return (u16)(u >> 16);
}

__device__ __forceinline__ float fexp2(float x) {
#if __has_builtin(__builtin_amdgcn_exp2f)
  return __builtin_amdgcn_exp2f(x);
#else
  return exp2f(x);
#endif
}

// MFMA via inline asm (D=C tied). 16x16x32 bf16: a/b = 8 bf16/lane (row|col = lane&15,
// k = 8*(lane>>4)+j); C/D: col = lane&15, row = 4*(lane>>4)+reg  [guide §3, m89/m91].
__device__ __forceinline__ void mfma16(f32x4& d, s16x8 a, s16x8 b) {
  asm volatile("v_mfma_f32_16x16x32_bf16 %0, %1, %2, %0" : "+v"(d) : "v"(a), "v"(b));
}
__device__ __forceinline__ f32x4 mfma16_z(s16x8 a, s16x8 b) {
  f32x4 d;
  asm volatile("v_mfma_f32_16x16x32_bf16 %0, %1, %2, 0" : "=&v"(d) : "v"(a), "v"(b));
  return d;
}

// async global->LDS, 16B per lane; LDS dest = wave-uniform base + lane*16 (m104).
__device__ __forceinline__ void g2lds16(const void* g, void* l) {
  __builtin_amdgcn_global_load_lds(
      (__attribute__((address_space(1))) void*)(uintptr_t)g,
      (__attribute__((address_space(3))) void*)(uint32_t)(uintptr_t)l, 16, 0, 0);
}

// ---------------- elementwise converts ----------------
__global__ __launch_bounds__(256) void cvt_f32_bf16(const float* __restrict__ in,
                                                    u16* __restrict__ out, int n) {
  int i = (blockIdx.x * 256 + threadIdx.x) * 4;
  if (i + 3 < n) {
    f32x4 v = *(const f32x4*)(in + i);
    u16x4 o = {f2bf(v.x), f2bf(v.y), f2bf(v.z), f2bf(v.w)};
    *(u16x4*)(out + i) = o;
  }
}

// 4x (1024x1024) weight converts into one contiguous buffer
__global__ __launch_bounds__(256) void cvt4(const float* __restrict__ a, const float* __restrict__ b,
                                            const float* __restrict__ c, const float* __restrict__ d,
                                            u16* __restrict__ out) {
  int z = blockIdx.y;
  const float* in = z == 0 ? a : z == 1 ? b : z == 2 ? c : d;
  int i = (blockIdx.x * 256 + threadIdx.x) * 4;
  f32x4 v = *(const f32x4*)(in + i);
  u16x4 o = {f2bf(v.x), f2bf(v.y), f2bf(v.z), f2bf(v.w)};
  *(u16x4*)(out + (size_t)z * 1048576 + i) = o;
}

// qkv_w (R=3072 x C=1024 f32) -> qkv_wT (C x R bf16)
__global__ __launch_bounds__(256) void transpose_f32_bf16(const float* __restrict__ in,
                                                          u16* __restrict__ out, int R, int C) {
  __shared__ u16 tile[32][33];
  int bx = blockIdx.x, by = blockIdx.y;
  int tx = threadIdx.x & 31, ty = threadIdx.x >> 5;
#pragma unroll
  for (int k = 0; k < 4; ++k)
    tile[ty + k * 8][tx] = f2bf(in[(size_t)(by * 32 + ty + k * 8) * C + bx * 32 + tx]);
  __syncthreads();
#pragma unroll
  for (int k = 0; k < 4; ++k)
    out[(size_t)(bx * 32 + ty + k * 8) * R + by * 32 + tx] = tile[tx][ty + k * 8];
}

// combined bias: cb[z][o] = sum_m W_z[o][m]*qkv_b[z*1024+m] + b_z[o]   (fp32 exact)
// z==0 (Q) additionally scaled by SCALE*log2e (softmax done in exp2 space).
__global__ __launch_bounds__(256) void cbias3(const float* __restrict__ qw, const float* __restrict__ kw,
                                              const float* __restrict__ vw, const float* __restrict__ qkvb,
                                              const float* __restrict__ qb, const float* __restrict__ kb,
                                              const float* __restrict__ vb, float* __restrict__ out) {
  int z = blockIdx.y;
  const float* w = z == 0 ? qw : (z == 1 ? kw : vw);
  const float* ba = z == 0 ? qb : (z == 1 ? kb : vb);
  const float* bi = qkvb + z * 1024;
  int o = blockIdx.x * 4 + (threadIdx.x >> 6);
  int lane = threadIdx.x & 63;
  float s = 0.f;
  for (int m = lane; m < 1024; m += 64) s += w[o * 1024 + m] * bi[m];
#pragma unroll
  for (int d = 1; d < 64; d <<= 1) s += __shfl_xor(s, d);
  if (lane == 0) {
    float fin = s + ba[o];
    if (z == 0) fin *= kQScale;
    out[z * 1024 + o] = fin;
  }
}

// attn_mask (2048x2048 int32) -> bit-packed rows (2048 x 32 u64), bit j = mask[row][w*64+j]==1
__global__ __launch_bounds__(256) void pack_mask(const int* __restrict__ m, u64* __restrict__ pm) {
  int row = blockIdx.x;
  int wv = threadIdx.x >> 6, lane = threadIdx.x & 63;
#pragma unroll
  for (int i = 0; i < 8; ++i) {
    int word = wv * 8 + i;
    u64 b = __ballot(m[(size_t)row * 2048 + word * 64 + lane] == 1);
    if (lane == 0) pm[(size_t)row * 32 + word] = b;
  }
}

// ---------------- NT GEMM: C[M,N] = A[M,K] * B[N,K]^T (+bias), m97-style 128^2 tile ----------
// z-batched via blockIdx.z with element strides. OUT_T in {u16(bf16), float}.
// scale_z0: epilogue scale applied only for blockIdx.z == 0 (bias added AFTER scale).
template <typename OUT_T, bool BIAS_PER_ROW>
__global__ __launch_bounds__(256, 2) void gemm_nt(const u16* __restrict__ A, int lda, long bsA,
                                                  const u16* __restrict__ B, int ldb, long bsB,
                                                  OUT_T* __restrict__ C, int ldc, long bsC,
                                                  const float* __restrict__ bias, long bsBias,
                                                  int NtilesN, int K, float scale_z0) {
  __shared__ __align__(16) u16 As[128 * 64];
  __shared__ __align__(16) u16 Bs[128 * 64];
  const int z = blockIdx.z;
  const float sc = (z == 0) ? scale_z0 : 1.f;
  A += (size_t)z * bsA; B += (size_t)z * bsB; C += (size_t)z * bsC;
  if (bias) bias += (size_t)z * bsBias;
  const int tm = blockIdx.x / NtilesN, tn = blockIdx.x % NtilesN;
  const int tid = threadIdx.x, lane = tid & 63, w = tid >> 6;
  const int wm = w >> 1, wn = w & 1;
  const int q = lane & 15, g = lane >> 4;
  f32x4 acc[4][4] = {};

  const u16* Ab = A + (size_t)(tm * 128 + (tid >> 3)) * lda + ((tid & 7) << 3);
  const u16* Bb = B + (size_t)(tn * 128 + (tid >> 3)) * ldb + ((tid & 7) << 3);
  char* AsW = (char*)As + (w << 10);
  char* BsW = (char*)Bs + (w << 10);

  for (int k0 = 0; k0 < K; k0 += 64) {
#pragma unroll
    for (int it = 0; it < 4; ++it) {
      g2lds16(Ab + (size_t)(it * 32) * lda + k0, AsW + it * 4096);
      g2lds16(Bb + (size_t)(it * 32) * ldb + k0, BsW + it * 4096);
    }
    __syncthreads();
#pragma unroll
    for (int kk = 0; kk < 2; ++kk) {
      s16x8 af[4], bf[4];
#pragma unroll
      for (int i = 0; i < 4; ++i)
        af[i] = *(const s16x8*)((const char*)As + (wm * 64 + i * 16 + q) * 128 + kk * 64 + g * 16);
#pragma unroll
      for (int i = 0; i < 4; ++i)
        bf[i] = *(const s16x8*)((const char*)Bs + (wn * 64 + i * 16 + q) * 128 + kk * 64 + g * 16);
#pragma unroll
      for (int mf = 0; mf < 4; ++mf)
#pragma unroll
        for (int nf = 0; nf < 4; ++nf) mfma16(acc[mf][nf], af[mf], bf[nf]);
    }
    __syncthreads();
  }
  asm volatile("s_nop 7\n\ts_nop 7");  // MFMA->VALU hazard (inline asm invisible to recognizer)
#pragma unroll
  for (int mf = 0; mf < 4; ++mf)
#pragma unroll
    for (int nf = 0; nf < 4; ++nf) {
      const int row = tm * 128 + wm * 64 + mf * 16 + g * 4;
      const int col = tn * 128 + wn * 64 + nf * 16 + q;
      float bc = (!BIAS_PER_ROW && bias) ? bias[col] : 0.f;
#pragma unroll
      for (int r = 0; r < 4; ++r) {
        float v = acc[mf][nf][r] * sc;
        if (bias) v += BIAS_PER_ROW ? bias[row + r] : bc;
        if constexpr (sizeof(OUT_T) == 2)
          C[(size_t)(row + r) * ldc + col] = (OUT_T)f2bf(v);
        else
          C[(size_t)(row + r) * ldc + col] = (OUT_T)v;
      }
    }
}

// ---------------- flash attention ----------------
// Q (pre-scaled by SCALE*log2e), K: (8192 x 1024) bf16 row=token, head h cols [h*128,h*128+128).
// Vt: (1024 x 8192) bf16, row = h*128+d, col = b*2048+s.
// 1024 blocks (flat, XCD-clustered decode), 4 waves x 16 q-rows, KV tile 64.
__global__ __launch_bounds__(256, 4) void attn_fwd(const u16* __restrict__ Qb, const u16* __restrict__ Kb,
                                                   const u16* __restrict__ Vt, const u64* __restrict__ pmask,
                                                   u16* __restrict__ Ob) {
  __shared__ __align__(16) char K_lds[16384];  // [64 kv][128 d], 16B-chunk XOR (kv&7) swizzle
  __shared__ __align__(16) char V_lds[16384];  // [128 d][64 kv], chunk XOR (d&7)
  __shared__ __align__(16) char P_lds[8192];   // [64 q][64 kv], chunk XOR (q&7)
  // XCD-clustered decode: block n -> XCD n%8 (m09). Give each XCD 4 complete (b,h)
  // groups (32 q-tiles each) so per-XCD K/V L2 footprint = 4 x 1MB = L2 size.
  const int n = blockIdx.x;
  const int slot = n >> 3;
  const int grp = (n & 7) * 4 + (slot >> 5);
  const int qt = slot & 31;
  const int h = grp & 7, b = grp >> 3;
  const int tid = threadIdx.x, w = tid >> 6, lane = tid & 63;
  const int q = lane & 15, g = lane >> 4;
  const int q0 = qt * 64;

  s16x8 qf[4];
#pragma unroll
  for (int kk = 0; kk < 4; ++kk)
    qf[kk] = *(const s16x8*)(Qb + (size_t)(b * 2048 + q0 + w * 16 + q) * 1024 +
                             h * 128 + kk * 32 + g * 8);

  f32x4 oacc[8] = {};
  float mrow[4], lrow[4];
#pragma unroll
  for (int r = 0; r < 4; ++r) { mrow[r] = -1e30f; lrow[r] = 0.f; }

  const int ksr = tid >> 4, ksc = tid & 15;  // K staging: slot row/chunk
  const int vsr = tid >> 3, vsc = tid & 7;   // V staging

  for (int s = 0; s < 32; ++s) {
    const int kv0 = s * 64;
#pragma unroll
    for (int it = 0; it < 4; ++it) {
      int kr = it * 16 + ksr;
      g2lds16(Kb + (size_t)(b * 2048 + kv0 + kr) * 1024 + h * 128 + ((ksc ^ (kr & 7)) << 3),
              K_lds + it * 4096 + (w << 10));
      int vr = it * 32 + vsr;
      g2lds16(Vt + (size_t)(h * 128 + vr) * 8192 + b * 2048 + kv0 + ((vsc ^ (vr & 7)) << 3),
              V_lds + it * 4096 + (w << 10));
    }
    __syncthreads();

    // S = Q K^T  (M=16 q-rows of this wave, N=64 kv) — scores already in log2 units
    f32x4 sacc[4];
#pragma unroll
    for (int kk = 0; kk < 4; ++kk) {
      s16x8 kf[4];
#pragma unroll
      for (int nn = 0; nn < 4; ++nn) {
        int kr = nn * 16 + q;
        kf[nn] = *(const s16x8*)(K_lds + kr * 256 + ((((kk << 2) + g) ^ (kr & 7)) << 4));
      }
#pragma unroll
      for (int nn = 0; nn < 4; ++nn) {
        if (kk == 0) sacc[nn] = mfma16_z(qf[0], kf[nn]);
        else         mfma16(sacc[nn], qf[kk], kf[nn]);
      }
    }
    asm volatile("s_nop 7\n\ts_nop 7");

    // mask + row max (lane owns rows g*4+r of this wave, cols nn*16+q)
    float mx[4];
    bool need = false;
#pragma unroll
    for (int r = 0; r < 4; ++r) {
      u64 pw = pmask[(size_t)(q0 + w * 16 + g * 4 + r) * 32 + s];
      float m2 = -1e30f;
#pragma unroll
      for (int nn = 0; nn < 4; ++nn) {
        float sv = sacc[nn][r];
        if ((pw >> (nn * 16 + q)) & 1) sv = -1e30f;
        sacc[nn][r] = sv;
        m2 = fmaxf(m2, sv);
      }
      m2 = fmaxf(m2, __shfl_xor(m2, 1)); m2 = fmaxf(m2, __shfl_xor(m2, 2));
      m2 = fmaxf(m2, __shfl_xor(m2, 4)); m2 = fmaxf(m2, __shfl_xor(m2, 8));
      mx[r] = m2;
      need |= (m2 > mrow[r] + 10.f);   // defer-max: P bounded by 2^10
    }
    if (__any(need)) {
#pragma unroll
      for (int r = 0; r < 4; ++r) {
        float mnew = fmaxf(mrow[r], mx[r]);
        float resc = fexp2(mrow[r] - mnew);
        mrow[r] = mnew;
        lrow[r] *= resc;
#pragma unroll
        for (int nd = 0; nd < 8; ++nd) oacc[nd][r] *= resc;
      }
    }
#pragma unroll
    for (int r = 0; r < 4; ++r) {
      float rs = 0.f;
#pragma unroll
      for (int nn = 0; nn < 4; ++nn) {
        float pv = fexp2(sacc[nn][r] - mrow[r]);
        sacc[nn][r] = pv;
        rs += pv;
      }
      rs += __shfl_xor(rs, 1); rs += __shfl_xor(rs, 2);
      rs += __shfl_xor(rs, 4); rs += __shfl_xor(rs, 8);
      lrow[r] += rs;
    }

    // P -> LDS (per-wave 2KB region, same-wave DS ordering => no barrier)
#pragma unroll
    for (int r = 0; r < 4; ++r) {
      int row = w * 16 + g * 4 + r;
#pragma unroll
      for (int nn = 0; nn < 4; ++nn) {
        int colb = (nn * 16 + q) << 1;
        int byt = row * 128 + ((((colb >> 4) ^ (row & 7)) << 4) | (colb & 15));
        *(u16*)(P_lds + byt) = f2bf(sacc[nn][r]);
      }
    }

    // O += P V   (K=64 kv)
#pragma unroll
    for (int kk = 0; kk < 2; ++kk) {
      int prow = w * 16 + q;
      s16x8 pf = *(const s16x8*)(P_lds + prow * 128 + ((((kk << 2) + g) ^ (prow & 7)) << 4));
#pragma unroll
      for (int nd = 0; nd < 8; ++nd) {
        int dr = nd * 16 + q;
        s16x8 vf = *(const s16x8*)(V_lds + dr * 128 + ((((kk << 2) + g) ^ (dr & 7)) << 4));
        mfma16(oacc[nd], pf, vf);
      }
    }
    __syncthreads();
  }

  asm volatile("s_nop 7\n\ts_nop 7");
  float rl[4];
#pragma unroll
  for (int r = 0; r < 4; ++r) rl[r] = 1.f / lrow[r];
#pragma unroll
  for (int nd = 0; nd < 8; ++nd)
#pragma unroll
    for (int r = 0; r < 4; ++r) {
      size_t trow = (size_t)(b * 2048 + q0 + w * 16 + g * 4 + r);
      Ob[trow * 1024 + h * 128 + nd * 16 + q] = f2bf(oacc[nd][r] * rl[r]);
    }
}

// ---------------- launcher ----------------
extern "C" void kernel_launch(void* const* d_in, const int* in_sizes, int n_in,
                              void* d_out, int out_size, void* d_ws, size_t ws_size,
                              hipStream_t stream) {
  (void)in_sizes; (void)n_in; (void)out_size; (void)ws_size;
  const float* x    = (const float*)d_in[0];
  const int*   am   = (const int*)d_in[1];
  const float* qkvw = (const float*)d_in[2];
  const float* qkvb = (const float*)d_in[3];
  const float* qw   = (const float*)d_in[4];
  const float* qb   = (const float*)d_in[5];
  const float* kw   = (const float*)d_in[6];
  const float* kb   = (const float*)d_in[7];
  const float* vw   = (const float*)d_in[8];
  const float* vb   = (const float*)d_in[9];
  const float* ow   = (const float*)d_in[10];
  const float* ob   = (const float*)d_in[11];

  char* p = (char*)d_ws;
  auto take = [&](size_t n) { char* r = p; p += (n + 255) & ~(size_t)255; return r; };
  u16* xb    = (u16*)take(8192ull * 1024 * 2);        // also reused as attention output
  u16* qkvwT = (u16*)take(1024ull * 3072 * 2);
  u16* wb4   = (u16*)take(4ull * 1048576 * 2);        // qwb,kwb,vwb,owb
  u16* comb3 = (u16*)take(3ull * 1048576 * 2);        // comb_q (pre-scaled), comb_k, comb_v
  float* cb3 = (float*)take(3ull * 1024 * 4);
  u16* QK2   = (u16*)take(2ull * 8192 * 1024 * 2);    // Qbuf, Kbuf
  u16* V2t   = (u16*)take(8192ull * 1024 * 2);
  u64* pm    = (u64*)take(2048ull * 32 * 8);
  u16* Obuf  = xb;                                    // alias: xb dead after projections

  cvt_f32_bf16<<<8192, 256, 0, stream>>>(x, xb, 8192 * 1024);
  cvt4<<<dim3(1024, 4), 256, 0, stream>>>(qw, kw, vw, ow, wb4);
  transpose_f32_bf16<<<dim3(32, 96), 256, 0, stream>>>(qkvw, qkvwT, 3072, 1024);
  cbias3<<<dim3(256, 3), 256, 0, stream>>>(qw, kw, vw, qkvb, qb, kb, vb, cb3);

  // combined weights: comb_z[o][i] = sum_m W_z[o][m] * qkv_w[z*1024+m][i]; z==0 scaled
  gemm_nt<u16, false><<<dim3(64, 1, 3), 256, 0, stream>>>(
      wb4, 1024, 1048576, qkvwT, 3072, 1024, comb3, 1024, 1048576, nullptr, 0, 8, 1024, kQScale);
  // Q,K projections (z=2): Q/K[t][o] = x[t]·comb_z[o] + cb_z[o]
  gemm_nt<u16, false><<<dim3(512, 1, 2), 256, 0, stream>>>(
      xb, 1024, 0, comb3, 1024, 1048576, QK2, 1024, 8192ll * 1024, cb3, 1024, 8, 1024, 1.f);
  // V transposed: V2t[o][t] = comb_v[o]·x[t] + cb_v[o]  (bias per row)
  gemm_nt<u16, true><<<dim3(512, 1, 1), 256, 0, stream>>>(
      comb3 + 2 * 1048576, 1024, 0, xb, 1024, 0, V2t, 8192, 0, cb3 + 2048, 0, 64, 1024, 1.f);

  pack_mask<<<2048, 256, 0, stream>>>(am, pm);
  attn_fwd<<<1024, 256, 0, stream>>>(QK2, QK2 + 8192ull * 1024, V2t, pm, Obuf);

  // out = O @ out_w^T + out_b  (fp32 output)
  gemm_nt<float, false><<<dim3(512, 1, 1), 256, 0, stream>>>(
      Obuf, 1024, 0, wb4 + 3 * 1048576, 1024, 0, (float*)d_out, 1024, 0, ob, 0, 8, 1024, 1.f);
}

// Round 3
// 274.162 us; speedup vs baseline: 1.2524x; 1.2524x over previous
//
#include <hip/hip_runtime.h>
#include <stdint.h>

typedef unsigned short u16;
typedef unsigned int u32;
typedef unsigned long long u64;
using f32x4 = __attribute__((ext_vector_type(4))) float;
using s16x8 = __attribute__((ext_vector_type(8))) short;
using u16x4 = __attribute__((ext_vector_type(4))) unsigned short;

static constexpr float kQScale = (float)(0.08838834764831845 * 1.4426950408889634);  // SCALE*log2(e)

__device__ __forceinline__ u16 f2bf(float f) {
  uint32_t u = __float_as_uint(f);
  u += 0x7fffu + ((u >> 16) & 1u);   // RNE
  return (u16)(u >> 16);
}

__device__ __forceinline__ float fexp2(float x) {
#if __has_builtin(__builtin_amdgcn_exp2f)
  return __builtin_amdgcn_exp2f(x);
#else
  return exp2f(x);
#endif
}

// MFMA via inline asm (D=C tied). 16x16x32 bf16: a/b = 8 bf16/lane (row|col = lane&15,
// k = 8*(lane>>4)+j); C/D: col = lane&15, row = 4*(lane>>4)+reg  [guide §3, m89/m91].
__device__ __forceinline__ void mfma16(f32x4& d, s16x8 a, s16x8 b) {
  asm volatile("v_mfma_f32_16x16x32_bf16 %0, %1, %2, %0" : "+v"(d) : "v"(a), "v"(b));
}
__device__ __forceinline__ f32x4 mfma16_z(s16x8 a, s16x8 b) {
  f32x4 d;
  asm volatile("v_mfma_f32_16x16x32_bf16 %0, %1, %2, 0" : "=&v"(d) : "v"(a), "v"(b));
  return d;
}

// async global->LDS, 16B per lane; LDS dest = wave-uniform base + lane*16 (m104).
__device__ __forceinline__ void g2lds16(const void* g, void* l) {
  __builtin_amdgcn_global_load_lds(
      (__attribute__((address_space(1))) void*)(uintptr_t)g,
      (__attribute__((address_space(3))) void*)(uint32_t)(uintptr_t)l, 16, 0, 0);
}

// ---------------- elementwise converts ----------------
__global__ __launch_bounds__(256) void cvt_f32_bf16(const float* __restrict__ in,
                                                    u16* __restrict__ out, int n) {
  int i = (blockIdx.x * 256 + threadIdx.x) * 4;
  if (i + 3 < n) {
    f32x4 v = *(const f32x4*)(in + i);
    u16x4 o = {f2bf(v.x), f2bf(v.y), f2bf(v.z), f2bf(v.w)};
    *(u16x4*)(out + i) = o;
  }
}

// 4x (1024x1024) weight converts into one contiguous buffer
__global__ __launch_bounds__(256) void cvt4(const float* __restrict__ a, const float* __restrict__ b,
                                            const float* __restrict__ c, const float* __restrict__ d,
                                            u16* __restrict__ out) {
  int z = blockIdx.y;
  const float* in = z == 0 ? a : z == 1 ? b : z == 2 ? c : d;
  int i = (blockIdx.x * 256 + threadIdx.x) * 4;
  f32x4 v = *(const f32x4*)(in + i);
  u16x4 o = {f2bf(v.x), f2bf(v.y), f2bf(v.z), f2bf(v.w)};
  *(u16x4*)(out + (size_t)z * 1048576 + i) = o;
}

// qkv_w (R=3072 x C=1024 f32) -> qkv_wT (C x R bf16)
__global__ __launch_bounds__(256) void transpose_f32_bf16(const float* __restrict__ in,
                                                          u16* __restrict__ out, int R, int C) {
  __shared__ u16 tile[32][33];
  int bx = blockIdx.x, by = blockIdx.y;
  int tx = threadIdx.x & 31, ty = threadIdx.x >> 5;
#pragma unroll
  for (int k = 0; k < 4; ++k)
    tile[ty + k * 8][tx] = f2bf(in[(size_t)(by * 32 + ty + k * 8) * C + bx * 32 + tx]);
  __syncthreads();
#pragma unroll
  for (int k = 0; k < 4; ++k)
    out[(size_t)(bx * 32 + ty + k * 8) * R + by * 32 + tx] = tile[tx][ty + k * 8];
}

// combined bias: cb[z][o] = sum_m W_z[o][m]*qkv_b[z*1024+m] + b_z[o]   (fp32 exact)
// z==0 (Q) additionally scaled by SCALE*log2e (softmax done in exp2 space).
__global__ __launch_bounds__(256) void cbias3(const float* __restrict__ qw, const float* __restrict__ kw,
                                              const float* __restrict__ vw, const float* __restrict__ qkvb,
                                              const float* __restrict__ qb, const float* __restrict__ kb,
                                              const float* __restrict__ vb, float* __restrict__ out) {
  int z = blockIdx.y;
  const float* w = z == 0 ? qw : (z == 1 ? kw : vw);
  const float* ba = z == 0 ? qb : (z == 1 ? kb : vb);
  const float* bi = qkvb + z * 1024;
  int o = blockIdx.x * 4 + (threadIdx.x >> 6);
  int lane = threadIdx.x & 63;
  float s = 0.f;
  for (int m = lane; m < 1024; m += 64) s += w[o * 1024 + m] * bi[m];
#pragma unroll
  for (int d = 1; d < 64; d <<= 1) s += __shfl_xor(s, d);
  if (lane == 0) {
    float fin = s + ba[o];
    if (z == 0) fin *= kQScale;
    out[z * 1024 + o] = fin;
  }
}

// attn_mask (2048x2048 int32) -> bit-packed rows (2048 x 32 u64), bit j = mask[row][w*64+j]==1
__global__ __launch_bounds__(256) void pack_mask(const int* __restrict__ m, u64* __restrict__ pm) {
  int row = blockIdx.x;
  int wv = threadIdx.x >> 6, lane = threadIdx.x & 63;
#pragma unroll
  for (int i = 0; i < 8; ++i) {
    int word = wv * 8 + i;
    u64 b = __ballot(m[(size_t)row * 2048 + word * 64 + lane] == 1);
    if (lane == 0) pm[(size_t)row * 32 + word] = b;
  }
}

// ---------------- NT GEMM: C[M,N] = A[M,K] * B[N,K]^T (+bias), 128^2 tile, 2-phase dbuf ----
template <typename OUT_T, bool BIAS_PER_ROW>
__global__ __launch_bounds__(256, 2) void gemm_nt(const u16* __restrict__ A, int lda, long bsA,
                                                  const u16* __restrict__ B, int ldb, long bsB,
                                                  OUT_T* __restrict__ C, int ldc, long bsC,
                                                  const float* __restrict__ bias, long bsBias,
                                                  int NtilesN, int K, float scale_z0) {
  __shared__ __align__(16) u16 As[2 * 128 * 64];
  __shared__ __align__(16) u16 Bs[2 * 128 * 64];
  const int z = blockIdx.z;
  const float sc = (z == 0) ? scale_z0 : 1.f;
  A += (size_t)z * bsA; B += (size_t)z * bsB; C += (size_t)z * bsC;
  if (bias) bias += (size_t)z * bsBias;
  const int tm = blockIdx.x / NtilesN, tn = blockIdx.x % NtilesN;
  const int tid = threadIdx.x, lane = tid & 63, w = tid >> 6;
  const int wm = w >> 1, wn = w & 1;
  const int q = lane & 15, g = lane >> 4;
  f32x4 acc[4][4] = {};

  const u16* Ab = A + (size_t)(tm * 128 + (tid >> 3)) * lda + ((tid & 7) << 3);
  const u16* Bb = B + (size_t)(tn * 128 + (tid >> 3)) * ldb + ((tid & 7) << 3);

  auto stage = [&](int buf, int k0) {
    char* dA = (char*)As + buf * 16384 + (w << 10);
    char* dB = (char*)Bs + buf * 16384 + (w << 10);
#pragma unroll
    for (int it = 0; it < 4; ++it) {
      g2lds16(Ab + (size_t)(it * 32) * lda + k0, dA + it * 4096);
      g2lds16(Bb + (size_t)(it * 32) * ldb + k0, dB + it * 4096);
    }
  };

  const int nT = K >> 6;
  stage(0, 0);
  __syncthreads();                       // compiler drains vmcnt before barrier
  for (int t = 0; t < nT; ++t) {
    if (t + 1 < nT) stage((t + 1) & 1, (t + 1) << 6);   // issue next tile (overlaps compute)
    const char* AsR = (const char*)As + (t & 1) * 16384;
    const char* BsR = (const char*)Bs + (t & 1) * 16384;
#pragma unroll
    for (int kk = 0; kk < 2; ++kk) {
      s16x8 af[4], bf[4];
#pragma unroll
      for (int i = 0; i < 4; ++i)
        af[i] = *(const s16x8*)(AsR + (wm * 64 + i * 16 + q) * 128 + kk * 64 + g * 16);
#pragma unroll
      for (int i = 0; i < 4; ++i)
        bf[i] = *(const s16x8*)(BsR + (wn * 64 + i * 16 + q) * 128 + kk * 64 + g * 16);
#pragma unroll
      for (int mf = 0; mf < 4; ++mf)
#pragma unroll
        for (int nf = 0; nf < 4; ++nf) mfma16(acc[mf][nf], af[mf], bf[nf]);
    }
    __syncthreads();                     // waits staged loads (in flight during compute)
  }
  asm volatile("s_nop 7\n\ts_nop 7");    // MFMA->VALU hazard (inline asm invisible to recognizer)
#pragma unroll
  for (int mf = 0; mf < 4; ++mf)
#pragma unroll
    for (int nf = 0; nf < 4; ++nf) {
      const int row = tm * 128 + wm * 64 + mf * 16 + g * 4;
      const int col = tn * 128 + wn * 64 + nf * 16 + q;
      float bc = (!BIAS_PER_ROW && bias) ? bias[col] : 0.f;
#pragma unroll
      for (int r = 0; r < 4; ++r) {
        float v = acc[mf][nf][r] * sc;
        if (bias) v += BIAS_PER_ROW ? bias[row + r] : bc;
        if constexpr (sizeof(OUT_T) == 2)
          C[(size_t)(row + r) * ldc + col] = (OUT_T)f2bf(v);
        else
          C[(size_t)(row + r) * ldc + col] = (OUT_T)v;
      }
    }
}

// ---------------- flash attention (fixed-max exp2 softmax, deferred l-reduce) ----------------
// Q (pre-scaled by SCALE*log2e), K: (8192 x 1024) bf16; Vt: (1024 x 8192) bf16 [d][token].
// 512 blocks (XCD-clustered), 4 waves x 32 q-rows (128-row q-tile), KV tile 64, 2-phase dbuf.
__global__ __launch_bounds__(256, 2) void attn_fwd(const u16* __restrict__ Qb, const u16* __restrict__ Kb,
                                                   const u16* __restrict__ Vt, const u64* __restrict__ pmask,
                                                   u16* __restrict__ Ob) {
  __shared__ __align__(16) char K_lds[2 * 16384];  // [64 kv][128 d], 16B-chunk XOR (kv&7)
  __shared__ __align__(16) char V_lds[2 * 16384];  // [128 d][64 kv], chunk XOR (d&7)
  __shared__ __align__(16) char P_lds[16384];      // [128 q][64 kv], chunk XOR (q&7)
  // XCD clustering: block n -> XCD n%8; 4 (b,h) groups x 16 qtiles per XCD -> 4MB K/V = L2.
  const int n = blockIdx.x;
  const int slot = n >> 3;
  const int grp = (n & 7) * 4 + (slot >> 4);
  const int qt = slot & 15;
  const int h = grp & 7, b = grp >> 3;
  const int tid = threadIdx.x, w = tid >> 6, lane = tid & 63;
  const int q = lane & 15, g = lane >> 4;
  const int q0 = qt * 128;

  s16x8 qf[2][4];
#pragma unroll
  for (int m = 0; m < 2; ++m)
#pragma unroll
    for (int kk = 0; kk < 4; ++kk)
      qf[m][kk] = *(const s16x8*)(Qb + (size_t)(b * 2048 + q0 + w * 32 + m * 16 + q) * 1024 +
                                  h * 128 + kk * 32 + g * 8);

  f32x4 oacc[2][8] = {};
  float lp[2][4] = {};

  const int ksr = tid >> 4, ksc = tid & 15;  // K staging: slot row/chunk
  const int vsr = tid >> 3, vsc = tid & 7;   // V staging

  auto stageKV = [&](int buf, int s2) {
    const int kv0 = s2 * 64;
    char* kb = K_lds + buf * 16384 + (w << 10);
    char* vb = V_lds + buf * 16384 + (w << 10);
#pragma unroll
    for (int it = 0; it < 4; ++it) {
      int kr = it * 16 + ksr;
      g2lds16(Kb + (size_t)(b * 2048 + kv0 + kr) * 1024 + h * 128 + ((ksc ^ (kr & 7)) << 3),
              kb + it * 4096);
      int vr = it * 32 + vsr;
      g2lds16(Vt + (size_t)(h * 128 + vr) * 8192 + b * 2048 + kv0 + ((vsc ^ (vr & 7)) << 3),
              vb + it * 4096);
    }
  };

  stageKV(0, 0);
  __syncthreads();

  for (int s = 0; s < 32; ++s) {
    const int cur = s & 1;
    if (s + 1 < 32) stageKV(cur ^ 1, s + 1);           // overlaps compute below
    const char* Kc = K_lds + cur * 16384;
    const char* Vc = V_lds + cur * 16384;

    // prefetch mask words (latency hides under QK^T)
    u64 pw[2][4];
#pragma unroll
    for (int m = 0; m < 2; ++m)
#pragma unroll
      for (int r = 0; r < 4; ++r)
        pw[m][r] = pmask[(size_t)(q0 + w * 32 + m * 16 + g * 4 + r) * 32 + s];

    // S = Q K^T (32 q-rows x 64 kv), scores in log2 units
    f32x4 sacc[2][4];
    __builtin_amdgcn_s_setprio(1);
#pragma unroll
    for (int kk = 0; kk < 4; ++kk) {
      s16x8 kf[4];
#pragma unroll
      for (int nn = 0; nn < 4; ++nn) {
        int kr = nn * 16 + q;
        kf[nn] = *(const s16x8*)(Kc + kr * 256 + ((((kk << 2) + g) ^ (kr & 7)) << 4));
      }
#pragma unroll
      for (int m = 0; m < 2; ++m)
#pragma unroll
        for (int nn = 0; nn < 4; ++nn) {
          if (kk == 0) sacc[m][nn] = mfma16_z(qf[m][0], kf[nn]);
          else         mfma16(sacc[m][nn], qf[m][kk], kf[nn]);
        }
    }
    __builtin_amdgcn_s_setprio(0);
    asm volatile("s_nop 7\n\ts_nop 7");

    // fixed-max softmax: P = exp2(s - 16), masked -> 0; per-lane partial l (no shuffles)
#pragma unroll
    for (int m = 0; m < 2; ++m)
#pragma unroll
      for (int r = 0; r < 4; ++r) {
        u32 lo = (u32)(pw[m][r] >> q);
        u32 hi = (u32)(pw[m][r] >> (32 + q));
#pragma unroll
        for (int nn = 0; nn < 4; ++nn) {
          u32 bit = (nn < 2) ? (lo >> (nn * 16)) : (hi >> ((nn - 2) * 16));
          float e = fexp2(sacc[nn == 0 ? m : m][nn][r] - 16.f);
          e = (bit & 1u) ? 0.f : e;
          sacc[m][nn][r] = e;
          lp[m][r] += e;
        }
      }

    // P -> LDS (per-wave region; same-wave DS ordering, no barrier)
#pragma unroll
    for (int m = 0; m < 2; ++m)
#pragma unroll
      for (int r = 0; r < 4; ++r) {
        int row = w * 32 + m * 16 + g * 4 + r;
#pragma unroll
        for (int nn = 0; nn < 4; ++nn) {
          int colb = (nn * 16 + q) << 1;
          int byt = row * 128 + ((((colb >> 4) ^ (row & 7)) << 4) | (colb & 15));
          *(u16*)(P_lds + byt) = f2bf(sacc[m][nn][r]);
        }
      }

    // O += P V   (K=64 kv)
    __builtin_amdgcn_s_setprio(1);
#pragma unroll
    for (int kk = 0; kk < 2; ++kk) {
      s16x8 pf[2];
#pragma unroll
      for (int m = 0; m < 2; ++m) {
        int prow = w * 32 + m * 16 + q;
        pf[m] = *(const s16x8*)(P_lds + prow * 128 + ((((kk << 2) + g) ^ (prow & 7)) << 4));
      }
#pragma unroll
      for (int nd = 0; nd < 8; ++nd) {
        int dr = nd * 16 + q;
        s16x8 vf = *(const s16x8*)(Vc + dr * 128 + ((((kk << 2) + g) ^ (dr & 7)) << 4));
#pragma unroll
        for (int m = 0; m < 2; ++m) mfma16(oacc[m][nd], pf[m], vf);
      }
    }
    __builtin_amdgcn_s_setprio(0);
    __syncthreads();                                   // drains staged loads for next iter
  }

  asm volatile("s_nop 7\n\ts_nop 7");
  // deferred l-reduction: once, over the 16 q-lanes
  float rl[2][4];
#pragma unroll
  for (int m = 0; m < 2; ++m)
#pragma unroll
    for (int r = 0; r < 4; ++r) {
      float v = lp[m][r];
      v += __shfl_xor(v, 1); v += __shfl_xor(v, 2);
      v += __shfl_xor(v, 4); v += __shfl_xor(v, 8);
      rl[m][r] = 1.f / v;
    }
#pragma unroll
  for (int m = 0; m < 2; ++m)
#pragma unroll
    for (int nd = 0; nd < 8; ++nd)
#pragma unroll
      for (int r = 0; r < 4; ++r) {
        size_t trow = (size_t)(b * 2048 + q0 + w * 32 + m * 16 + g * 4 + r);
        Ob[trow * 1024 + h * 128 + nd * 16 + q] = f2bf(oacc[m][nd][r] * rl[m][r]);
      }
}

// ---------------- launcher ----------------
extern "C" void kernel_launch(void* const* d_in, const int* in_sizes, int n_in,
                              void* d_out, int out_size, void* d_ws, size_t ws_size,
                              hipStream_t stream) {
  (void)in_sizes; (void)n_in; (void)out_size; (void)ws_size;
  const float* x    = (const float*)d_in[0];
  const int*   am   = (const int*)d_in[1];
  const float* qkvw = (const float*)d_in[2];
  const float* qkvb = (const float*)d_in[3];
  const float* qw   = (const float*)d_in[4];
  const float* qb   = (const float*)d_in[5];
  const float* kw   = (const float*)d_in[6];
  const float* kb   = (const float*)d_in[7];
  const float* vw   = (const float*)d_in[8];
  const float* vb   = (const float*)d_in[9];
  const float* ow   = (const float*)d_in[10];
  const float* ob   = (const float*)d_in[11];

  char* p = (char*)d_ws;
  auto take = [&](size_t n) { char* r = p; p += (n + 255) & ~(size_t)255; return r; };
  u16* xb    = (u16*)take(8192ull * 1024 * 2);        // also reused as attention output
  u16* qkvwT = (u16*)take(1024ull * 3072 * 2);
  u16* wb4   = (u16*)take(4ull * 1048576 * 2);        // qwb,kwb,vwb,owb
  u16* comb3 = (u16*)take(3ull * 1048576 * 2);        // comb_q (pre-scaled), comb_k, comb_v
  float* cb3 = (float*)take(3ull * 1024 * 4);
  u16* QK2   = (u16*)take(2ull * 8192 * 1024 * 2);    // Qbuf, Kbuf
  u16* V2t   = (u16*)take(8192ull * 1024 * 2);
  u64* pm    = (u64*)take(2048ull * 32 * 8);
  u16* Obuf  = xb;                                    // alias: xb dead after projections

  cvt_f32_bf16<<<8192, 256, 0, stream>>>(x, xb, 8192 * 1024);
  cvt4<<<dim3(1024, 4), 256, 0, stream>>>(qw, kw, vw, ow, wb4);
  transpose_f32_bf16<<<dim3(32, 96), 256, 0, stream>>>(qkvw, qkvwT, 3072, 1024);
  cbias3<<<dim3(256, 3), 256, 0, stream>>>(qw, kw, vw, qkvb, qb, kb, vb, cb3);

  // combined weights: comb_z[o][i] = sum_m W_z[o][m] * qkv_w[z*1024+m][i]; z==0 scaled
  gemm_nt<u16, false><<<dim3(64, 1, 3), 256, 0, stream>>>(
      wb4, 1024, 1048576, qkvwT, 3072, 1024, comb3, 1024, 1048576, nullptr, 0, 8, 1024, kQScale);
  // Q,K projections (z=2): Q/K[t][o] = x[t]·comb_z[o] + cb_z[o]
  gemm_nt<u16, false><<<dim3(512, 1, 2), 256, 0, stream>>>(
      xb, 1024, 0, comb3, 1024, 1048576, QK2, 1024, 8192ll * 1024, cb3, 1024, 8, 1024, 1.f);
  // V transposed: V2t[o][t] = comb_v[o]·x[t] + cb_v[o]  (bias per row)
  gemm_nt<u16, true><<<dim3(512, 1, 1), 256, 0, stream>>>(
      comb3 + 2 * 1048576, 1024, 0, xb, 1024, 0, V2t, 8192, 0, cb3 + 2048, 0, 64, 1024, 1.f);

  pack_mask<<<2048, 256, 0, stream>>>(am, pm);
  attn_fwd<<<512, 256, 0, stream>>>(QK2, QK2 + 8192ull * 1024, V2t, pm, Obuf);

  // out = O @ out_w^T + out_b  (fp32 output)
  gemm_nt<float, false><<<dim3(512, 1, 1), 256, 0, stream>>>(
      Obuf, 1024, 0, wb4 + 3 * 1048576, 1024, 0, (float*)d_out, 1024, 0, ob, 0, 8, 1024, 1.f);
}

// Round 4
// 261.638 us; speedup vs baseline: 1.3124x; 1.0479x over previous
//
#include <hip/hip_runtime.h>
#include <stdint.h>

typedef unsigned short u16;
typedef unsigned int u32;
typedef unsigned long long u64;
using f32x4 = __attribute__((ext_vector_type(4))) float;
using f32x16 = __attribute__((ext_vector_type(16))) float;
using s16x8 = __attribute__((ext_vector_type(8))) short;
using u16x4 = __attribute__((ext_vector_type(4))) unsigned short;
using u32x4 = __attribute__((ext_vector_type(4))) u32;

static constexpr float kQScale = (float)(0.08838834764831845 * 1.4426950408889634);  // SCALE*log2(e)

__device__ __forceinline__ u16 f2bf(float f) {
  uint32_t u = __float_as_uint(f);
  u += 0x7fffu + ((u >> 16) & 1u);   // RNE
  return (u16)(u >> 16);
}

__device__ __forceinline__ float fexp2(float x) {
#if __has_builtin(__builtin_amdgcn_exp2f)
  return __builtin_amdgcn_exp2f(x);
#else
  return exp2f(x);
#endif
}

__device__ __forceinline__ u32 cvtpk(float lo, float hi) {
  u32 r;
  asm("v_cvt_pk_bf16_f32 %0, %1, %2" : "=v"(r) : "v"(lo), "v"(hi));
  return r;
}

// 16x16x32 bf16 MFMA (D=C tied): C/D col=lane&15, row=4*(lane>>4)+reg [m89/m91].
__device__ __forceinline__ void mfma16(f32x4& d, s16x8 a, s16x8 b) {
  asm volatile("v_mfma_f32_16x16x32_bf16 %0, %1, %2, %0" : "+v"(d) : "v"(a), "v"(b));
}
// 32x32x16 bf16 MFMA: A row=lane&31,k=8*(lane>>5)+j; B col=lane&31,k=8*(lane>>5)+j;
// C/D col=lane&31, row=(reg&3)+8*(reg>>2)+4*(lane>>5) [m74/m101].
__device__ __forceinline__ void mfma32(f32x16& d, s16x8 a, s16x8 b) {
  asm volatile("v_mfma_f32_32x32x16_bf16 %0, %1, %2, %0" : "+v"(d) : "v"(a), "v"(b));
}

// async global->LDS, 16B per lane; LDS dest = wave-uniform base + lane*16 (m104).
__device__ __forceinline__ void g2lds16(const void* g, void* l) {
  __builtin_amdgcn_global_load_lds(
      (__attribute__((address_space(1))) void*)(uintptr_t)g,
      (__attribute__((address_space(3))) void*)(uint32_t)(uintptr_t)l, 16, 0, 0);
}

// ---------------- elementwise converts ----------------
__global__ __launch_bounds__(256) void cvt_f32_bf16(const float* __restrict__ in,
                                                    u16* __restrict__ out, int n) {
  int i = (blockIdx.x * 256 + threadIdx.x) * 4;
  if (i + 3 < n) {
    f32x4 v = *(const f32x4*)(in + i);
    u16x4 o = {f2bf(v.x), f2bf(v.y), f2bf(v.z), f2bf(v.w)};
    *(u16x4*)(out + i) = o;
  }
}

__global__ __launch_bounds__(256) void cvt4(const float* __restrict__ a, const float* __restrict__ b,
                                            const float* __restrict__ c, const float* __restrict__ d,
                                            u16* __restrict__ out) {
  int z = blockIdx.y;
  const float* in = z == 0 ? a : z == 1 ? b : z == 2 ? c : d;
  int i = (blockIdx.x * 256 + threadIdx.x) * 4;
  f32x4 v = *(const f32x4*)(in + i);
  u16x4 o = {f2bf(v.x), f2bf(v.y), f2bf(v.z), f2bf(v.w)};
  *(u16x4*)(out + (size_t)z * 1048576 + i) = o;
}

// qkv_w (R=3072 x C=1024 f32) -> qkv_wT (C x R bf16)
__global__ __launch_bounds__(256) void transpose_f32_bf16(const float* __restrict__ in,
                                                          u16* __restrict__ out, int R, int C) {
  __shared__ u16 tile[32][33];
  int bx = blockIdx.x, by = blockIdx.y;
  int tx = threadIdx.x & 31, ty = threadIdx.x >> 5;
#pragma unroll
  for (int k = 0; k < 4; ++k)
    tile[ty + k * 8][tx] = f2bf(in[(size_t)(by * 32 + ty + k * 8) * C + bx * 32 + tx]);
  __syncthreads();
#pragma unroll
  for (int k = 0; k < 4; ++k)
    out[(size_t)(bx * 32 + ty + k * 8) * R + by * 32 + tx] = tile[tx][ty + k * 8];
}

// combined bias (fp32 exact); z==0 (Q) scaled by SCALE*log2e
__global__ __launch_bounds__(256) void cbias3(const float* __restrict__ qw, const float* __restrict__ kw,
                                              const float* __restrict__ vw, const float* __restrict__ qkvb,
                                              const float* __restrict__ qb, const float* __restrict__ kb,
                                              const float* __restrict__ vb, float* __restrict__ out) {
  int z = blockIdx.y;
  const float* w = z == 0 ? qw : (z == 1 ? kw : vw);
  const float* ba = z == 0 ? qb : (z == 1 ? kb : vb);
  const float* bi = qkvb + z * 1024;
  int o = blockIdx.x * 4 + (threadIdx.x >> 6);
  int lane = threadIdx.x & 63;
  float s = 0.f;
  for (int m = lane; m < 1024; m += 64) s += w[o * 1024 + m] * bi[m];
#pragma unroll
  for (int d = 1; d < 64; d <<= 1) s += __shfl_xor(s, d);
  if (lane == 0) {
    float fin = s + ba[o];
    if (z == 0) fin *= kQScale;
    out[z * 1024 + o] = fin;
  }
}

// attn_mask -> bit-packed rows (2048 x 32 u64)
__global__ __launch_bounds__(256) void pack_mask(const int* __restrict__ m, u64* __restrict__ pm) {
  int row = blockIdx.x;
  int wv = threadIdx.x >> 6, lane = threadIdx.x & 63;
#pragma unroll
  for (int i = 0; i < 8; ++i) {
    int word = wv * 8 + i;
    u64 b = __ballot(m[(size_t)row * 2048 + word * 64 + lane] == 1);
    if (lane == 0) pm[(size_t)row * 32 + word] = b;
  }
}

// ---------------- NT GEMM: C[M,N] = A[M,K] * B[N,K]^T (+bias), m97-style single-buffer ----
template <typename OUT_T, bool BIAS_PER_ROW>
__global__ __launch_bounds__(256, 2) void gemm_nt(const u16* __restrict__ A, int lda, long bsA,
                                                  const u16* __restrict__ B, int ldb, long bsB,
                                                  OUT_T* __restrict__ C, int ldc, long bsC,
                                                  const float* __restrict__ bias, long bsBias,
                                                  int NtilesN, int K, float scale_z0) {
  __shared__ __align__(16) u16 As[128 * 64];
  __shared__ __align__(16) u16 Bs[128 * 64];
  const int z = blockIdx.z;
  const float sc = (z == 0) ? scale_z0 : 1.f;
  A += (size_t)z * bsA; B += (size_t)z * bsB; C += (size_t)z * bsC;
  if (bias) bias += (size_t)z * bsBias;
  const int tm = blockIdx.x / NtilesN, tn = blockIdx.x % NtilesN;
  const int tid = threadIdx.x, lane = tid & 63, w = tid >> 6;
  const int wm = w >> 1, wn = w & 1;
  const int q = lane & 15, g = lane >> 4;
  f32x4 acc[4][4] = {};

  const u16* Ab = A + (size_t)(tm * 128 + (tid >> 3)) * lda + ((tid & 7) << 3);
  const u16* Bb = B + (size_t)(tn * 128 + (tid >> 3)) * ldb + ((tid & 7) << 3);
  char* AsW = (char*)As + (w << 10);
  char* BsW = (char*)Bs + (w << 10);

  for (int k0 = 0; k0 < K; k0 += 64) {
#pragma unroll
    for (int it = 0; it < 4; ++it) {
      g2lds16(Ab + (size_t)(it * 32) * lda + k0, AsW + it * 4096);
      g2lds16(Bb + (size_t)(it * 32) * ldb + k0, BsW + it * 4096);
    }
    __syncthreads();
#pragma unroll
    for (int kk = 0; kk < 2; ++kk) {
      s16x8 af[4], bf[4];
#pragma unroll
      for (int i = 0; i < 4; ++i)
        af[i] = *(const s16x8*)((const char*)As + (wm * 64 + i * 16 + q) * 128 + kk * 64 + g * 16);
#pragma unroll
      for (int i = 0; i < 4; ++i)
        bf[i] = *(const s16x8*)((const char*)Bs + (wn * 64 + i * 16 + q) * 128 + kk * 64 + g * 16);
#pragma unroll
      for (int mf = 0; mf < 4; ++mf)
#pragma unroll
        for (int nf = 0; nf < 4; ++nf) mfma16(acc[mf][nf], af[mf], bf[nf]);
    }
    __syncthreads();
  }
  asm volatile("s_nop 7\n\ts_nop 7");
#pragma unroll
  for (int mf = 0; mf < 4; ++mf)
#pragma unroll
    for (int nf = 0; nf < 4; ++nf) {
      const int row = tm * 128 + wm * 64 + mf * 16 + g * 4;
      const int col = tn * 128 + wn * 64 + nf * 16 + q;
      float bc = (!BIAS_PER_ROW && bias) ? bias[col] : 0.f;
#pragma unroll
      for (int r = 0; r < 4; ++r) {
        float v = acc[mf][nf][r] * sc;
        if (bias) v += BIAS_PER_ROW ? bias[row + r] : bc;
        if constexpr (sizeof(OUT_T) == 2)
          C[(size_t)(row + r) * ldc + col] = (OUT_T)f2bf(v);
        else
          C[(size_t)(row + r) * ldc + col] = (OUT_T)v;
      }
    }
}

// ---------------- flash attention: swapped QK^T (32x32), in-register P ----------------
// Q (pre-scaled by SCALE*log2e), K: (8192 x 1024) bf16; Vt: (1024 x 8192) bf16 [d][token].
// 512 blocks (XCD-clustered), 4 waves x 32 q-rows, KV tile 64, 2-phase dbuf, fixed-max exp2.
__global__ __launch_bounds__(256, 2) void attn_fwd(const u16* __restrict__ Qb, const u16* __restrict__ Kb,
                                                   const u16* __restrict__ Vt, const u64* __restrict__ pmask,
                                                   u16* __restrict__ Ob) {
  __shared__ __align__(16) char K_lds[2 * 16384];  // [64 kv][128 d], 16B-chunk XOR (kv&15)
  __shared__ __align__(16) char V_lds[2 * 16384];  // [128 d][64 kv], 16B-chunk XOR (d&7)
  __shared__ float l_red[4][32];
  const int n = blockIdx.x;
  const int slot = n >> 3;
  const int grp = (n & 7) * 4 + (slot >> 4);
  const int qt = slot & 15;
  const int h = grp & 7, b = grp >> 3;
  const int tid = threadIdx.x, w = tid >> 6, lane = tid & 63;
  const int ql = lane & 31;       // q within wave tile (QK^T B-col / O D-col)
  const int hi = lane >> 5;
  const int q0 = qt * 128;

  // Q as 32x32 B-frags: qf[kd] = Q[q0+w*32+ql][16*kd + 8*hi + j]
  s16x8 qf[8];
  const u16* qrow = Qb + (size_t)(b * 2048 + q0 + w * 32 + ql) * 1024 + h * 128 + 8 * hi;
#pragma unroll
  for (int kd = 0; kd < 8; ++kd) qf[kd] = *(const s16x8*)(qrow + 16 * kd);

  f32x16 oacc[4] = {};   // dt: O[q=crow(reg,hi)][d = dt*32+ql]
  float lp = 0.f;        // per-lane partial row-sum (q = ql; kv subset of this lane)

  const int ksr = tid >> 4, ksc = tid & 15;  // K staging: row/slot
  const int vsr = tid >> 3, vsc = tid & 7;   // V staging: row/slot
  const int sw = ql & 15;                    // K read swizzle key (row&15)

  auto stageKV = [&](int buf, int s2) {
    const int kv0 = s2 * 64;
    char* kb = K_lds + buf * 16384 + (w << 10);
    char* vb = V_lds + buf * 16384 + (w << 10);
#pragma unroll
    for (int it = 0; it < 4; ++it) {
      int kr = it * 16 + ksr;
      g2lds16(Kb + (size_t)(b * 2048 + kv0 + kr) * 1024 + h * 128 + ((ksc ^ (kr & 15)) << 3),
              kb + it * 4096);
      int vr = it * 32 + vsr;
      g2lds16(Vt + (size_t)(h * 128 + vr) * 8192 + b * 2048 + kv0 + ((vsc ^ (vr & 7)) << 3),
              vb + it * 4096);
    }
  };

  stageKV(0, 0);
  __syncthreads();

  for (int s = 0; s < 32; ++s) {
    const int cur = s & 1;
    if (s + 1 < 32) stageKV(cur ^ 1, s + 1);
    const char* Kc = K_lds + cur * 16384;
    const char* Vc = V_lds + cur * 16384;

    u64 pw = pmask[(size_t)(q0 + w * 32 + ql) * 32 + s];

    // S^T[kv][q] = K · Q^T : A = K-frag (row kv), B = Q-frag (col q)
    f32x16 sacc0 = {}, sacc1 = {};
    __builtin_amdgcn_s_setprio(1);
#pragma unroll
    for (int kd = 0; kd < 8; ++kd) {
      int c = (2 * kd + hi) ^ sw;
      s16x8 kf0 = *(const s16x8*)(Kc + ql * 256 + (c << 4));
      s16x8 kf1 = *(const s16x8*)(Kc + (32 + ql) * 256 + (c << 4));
      mfma32(sacc0, kf0, qf[kd]);
      mfma32(sacc1, kf1, qf[kd]);
    }
    __builtin_amdgcn_s_setprio(0);
    asm volatile("s_nop 7\n\ts_nop 7");

    // in-register softmax: lane holds S^T[kv = 32*nt + (reg&3)+8*(reg>>2)+4*hi][q=ql]
    u32 Wp[8][2];   // group u = 4*nt + t  (kv = 8u + 4hi + j), packed bf16 pairs
#pragma unroll
    for (int nt = 0; nt < 2; ++nt) {
      u32 halfm = ((u32)(pw >> (32 * nt))) >> (4 * hi);
#pragma unroll
      for (int t = 0; t < 4; ++t) {
        float e[4];
#pragma unroll
        for (int j = 0; j < 4; ++j) {
          float ev = fexp2((nt == 0 ? sacc0[4 * t + j] : sacc1[4 * t + j]) - 16.f);
          if ((halfm >> (8 * t + j)) & 1u) ev = 0.f;
          e[j] = ev;
          lp += ev;
        }
        Wp[nt * 4 + t][0] = cvtpk(e[0], e[1]);
        Wp[nt * 4 + t][1] = cvtpk(e[2], e[3]);
      }
    }

    // exchange odd/even groups with lane^32, assemble PV A-frags pa[ks] (kv = 16ks+8hi+0..7)
    s16x8 pa[4];
#pragma unroll
    for (int ks = 0; ks < 4; ++ks) {
      u32 s0 = hi ? Wp[2 * ks][0] : Wp[2 * ks + 1][0];
      u32 s1 = hi ? Wp[2 * ks][1] : Wp[2 * ks + 1][1];
      u32 r0 = (u32)__shfl_xor((int)s0, 32);
      u32 r1 = (u32)__shfl_xor((int)s1, 32);
      u32 o0 = hi ? Wp[2 * ks + 1][0] : Wp[2 * ks][0];
      u32 o1 = hi ? Wp[2 * ks + 1][1] : Wp[2 * ks][1];
      u32x4 wv;
      wv.x = hi ? r0 : o0;
      wv.y = hi ? r1 : o1;
      wv.z = hi ? o0 : r0;
      wv.w = hi ? o1 : r1;
      pa[ks] = __builtin_bit_cast(s16x8, wv);
    }
    asm volatile("s_nop 3");   // VALU->MFMA SrcA hazard margin

    // O += P V : B = V-frag (k=kv, col=d)
    __builtin_amdgcn_s_setprio(1);
#pragma unroll
    for (int ks = 0; ks < 4; ++ks) {
#pragma unroll
      for (int dt = 0; dt < 4; ++dt) {
        int vrow = dt * 32 + ql;
        s16x8 vf = *(const s16x8*)(Vc + vrow * 128 + ((((2 * ks + hi)) ^ (vrow & 7)) << 4));
        mfma32(oacc[dt], pa[ks], vf);
      }
    }
    __builtin_amdgcn_s_setprio(0);
    __syncthreads();
  }

  asm volatile("s_nop 7\n\ts_nop 7");
  // row-sum finalize: lanes l and l^32 hold complementary kv subsets of q=ql
  lp += __shfl_xor(lp, 32);
  if (lane < 32) l_red[w][lane] = 1.f / lp;   // same-wave DS ordering
  float rl[16];
#pragma unroll
  for (int reg = 0; reg < 16; ++reg)
    rl[reg] = l_red[w][(reg & 3) + 8 * (reg >> 2) + 4 * hi];
#pragma unroll
  for (int dt = 0; dt < 4; ++dt)
#pragma unroll
    for (int reg = 0; reg < 16; ++reg) {
      int qr = (reg & 3) + 8 * (reg >> 2) + 4 * hi;
      size_t trow = (size_t)(b * 2048 + q0 + w * 32 + qr);
      Ob[trow * 1024 + h * 128 + dt * 32 + ql] = f2bf(oacc[dt][reg] * rl[reg]);
    }
}

// ---------------- launcher ----------------
extern "C" void kernel_launch(void* const* d_in, const int* in_sizes, int n_in,
                              void* d_out, int out_size, void* d_ws, size_t ws_size,
                              hipStream_t stream) {
  (void)in_sizes; (void)n_in; (void)out_size; (void)ws_size;
  const float* x    = (const float*)d_in[0];
  const int*   am   = (const int*)d_in[1];
  const float* qkvw = (const float*)d_in[2];
  const float* qkvb = (const float*)d_in[3];
  const float* qw   = (const float*)d_in[4];
  const float* qb   = (const float*)d_in[5];
  const float* kw   = (const float*)d_in[6];
  const float* kb   = (const float*)d_in[7];
  const float* vw   = (const float*)d_in[8];
  const float* vb   = (const float*)d_in[9];
  const float* ow   = (const float*)d_in[10];
  const float* ob   = (const float*)d_in[11];

  char* p = (char*)d_ws;
  auto take = [&](size_t n) { char* r = p; p += (n + 255) & ~(size_t)255; return r; };
  u16* xb    = (u16*)take(8192ull * 1024 * 2);        // also reused as attention output
  u16* qkvwT = (u16*)take(1024ull * 3072 * 2);
  u16* wb4   = (u16*)take(4ull * 1048576 * 2);        // qwb,kwb,vwb,owb
  u16* comb3 = (u16*)take(3ull * 1048576 * 2);        // comb_q (pre-scaled), comb_k, comb_v
  float* cb3 = (float*)take(3ull * 1024 * 4);
  u16* QK2   = (u16*)take(2ull * 8192 * 1024 * 2);    // Qbuf, Kbuf
  u16* V2t   = (u16*)take(8192ull * 1024 * 2);
  u64* pm    = (u64*)take(2048ull * 32 * 8);
  u16* Obuf  = xb;                                    // alias: xb dead after projections

  cvt_f32_bf16<<<8192, 256, 0, stream>>>(x, xb, 8192 * 1024);
  cvt4<<<dim3(1024, 4), 256, 0, stream>>>(qw, kw, vw, ow, wb4);
  transpose_f32_bf16<<<dim3(32, 96), 256, 0, stream>>>(qkvw, qkvwT, 3072, 1024);
  cbias3<<<dim3(256, 3), 256, 0, stream>>>(qw, kw, vw, qkvb, qb, kb, vb, cb3);

  // combined weights: comb_z[o][i] = sum_m W_z[o][m] * qkv_w[z*1024+m][i]; z==0 scaled
  gemm_nt<u16, false><<<dim3(64, 1, 3), 256, 0, stream>>>(
      wb4, 1024, 1048576, qkvwT, 3072, 1024, comb3, 1024, 1048576, nullptr, 0, 8, 1024, kQScale);
  // Q,K projections (z=2)
  gemm_nt<u16, false><<<dim3(512, 1, 2), 256, 0, stream>>>(
      xb, 1024, 0, comb3, 1024, 1048576, QK2, 1024, 8192ll * 1024, cb3, 1024, 8, 1024, 1.f);
  // V transposed: V2t[o][t] = comb_v[o]·x[t] + cb_v[o]  (bias per row)
  gemm_nt<u16, true><<<dim3(512, 1, 1), 256, 0, stream>>>(
      comb3 + 2 * 1048576, 1024, 0, xb, 1024, 0, V2t, 8192, 0, cb3 + 2048, 0, 64, 1024, 1.f);

  pack_mask<<<2048, 256, 0, stream>>>(am, pm);
  attn_fwd<<<512, 256, 0, stream>>>(QK2, QK2 + 8192ull * 1024, V2t, pm, Obuf);

  // out = O @ out_w^T + out_b  (fp32 output)
  gemm_nt<float, false><<<dim3(512, 1, 1), 256, 0, stream>>>(
      Obuf, 1024, 0, wb4 + 3 * 1048576, 1024, 0, (float*)d_out, 1024, 0, ob, 0, 8, 1024, 1.f);
}

// Round 5
// 244.828 us; speedup vs baseline: 1.4025x; 1.0687x over previous
//
#include <hip/hip_runtime.h>
#include <stdint.h>

typedef unsigned short u16;
typedef unsigned int u32;
typedef unsigned long long u64;
using f32x4 = __attribute__((ext_vector_type(4))) float;
using f32x16 = __attribute__((ext_vector_type(16))) float;
using s16x8 = __attribute__((ext_vector_type(8))) short;
using u16x4 = __attribute__((ext_vector_type(4))) unsigned short;
using u32x4 = __attribute__((ext_vector_type(4))) u32;

static constexpr float kQScale = (float)(0.08838834764831845 * 1.4426950408889634);  // SCALE*log2(e)

__device__ __forceinline__ u16 f2bf(float f) {
  uint32_t u = __float_as_uint(f);
  u += 0x7fffu + ((u >> 16) & 1u);   // RNE
  return (u16)(u >> 16);
}

__device__ __forceinline__ float fexp2(float x) {
#if __has_builtin(__builtin_amdgcn_exp2f)
  return __builtin_amdgcn_exp2f(x);
#else
  return exp2f(x);
#endif
}

__device__ __forceinline__ u32 cvtpk(float lo, float hi) {
  u32 r;
  asm("v_cvt_pk_bf16_f32 %0, %1, %2" : "=v"(r) : "v"(lo), "v"(hi));
  return r;
}

// 16x16x32 bf16 MFMA (D=C tied): C/D col=lane&15, row=4*(lane>>4)+reg [m89/m91].
__device__ __forceinline__ void mfma16(f32x4& d, s16x8 a, s16x8 b) {
  asm volatile("v_mfma_f32_16x16x32_bf16 %0, %1, %2, %0" : "+v"(d) : "v"(a), "v"(b));
}
// 32x32x16 bf16 MFMA: A row=lane&31,k=8*(lane>>5)+j; B col=lane&31;
// C/D col=lane&31, row=(reg&3)+8*(reg>>2)+4*(lane>>5) [m74/m101].
__device__ __forceinline__ void mfma32(f32x16& d, s16x8 a, s16x8 b) {
  asm volatile("v_mfma_f32_32x32x16_bf16 %0, %1, %2, %0" : "+v"(d) : "v"(a), "v"(b));
}
__device__ __forceinline__ f32x16 mfma32_z(s16x8 a, s16x8 b) {
  f32x16 d;
  asm volatile("v_mfma_f32_32x32x16_bf16 %0, %1, %2, 0" : "=&v"(d) : "v"(a), "v"(b));
  return d;
}

// async global->LDS, 16B per lane; LDS dest = wave-uniform base + lane*16 (m104).
__device__ __forceinline__ void g2lds16(const void* g, void* l) {
  __builtin_amdgcn_global_load_lds(
      (__attribute__((address_space(1))) void*)(uintptr_t)g,
      (__attribute__((address_space(3))) void*)(uint32_t)(uintptr_t)l, 16, 0, 0);
}

#define BAR() asm volatile("s_barrier" ::: "memory")

// ---------------- elementwise converts ----------------
__global__ __launch_bounds__(256) void cvt_f32_bf16(const float* __restrict__ in,
                                                    u16* __restrict__ out, int n) {
  int i = (blockIdx.x * 256 + threadIdx.x) * 4;
  if (i + 3 < n) {
    f32x4 v = *(const f32x4*)(in + i);
    u16x4 o = {f2bf(v.x), f2bf(v.y), f2bf(v.z), f2bf(v.w)};
    *(u16x4*)(out + i) = o;
  }
}

__global__ __launch_bounds__(256) void cvt4(const float* __restrict__ a, const float* __restrict__ b,
                                            const float* __restrict__ c, const float* __restrict__ d,
                                            u16* __restrict__ out) {
  int z = blockIdx.y;
  const float* in = z == 0 ? a : z == 1 ? b : z == 2 ? c : d;
  int i = (blockIdx.x * 256 + threadIdx.x) * 4;
  f32x4 v = *(const f32x4*)(in + i);
  u16x4 o = {f2bf(v.x), f2bf(v.y), f2bf(v.z), f2bf(v.w)};
  *(u16x4*)(out + (size_t)z * 1048576 + i) = o;
}

// qkv_w (R=3072 x C=1024 f32) -> qkv_wT (C x R bf16)
__global__ __launch_bounds__(256) void transpose_f32_bf16(const float* __restrict__ in,
                                                          u16* __restrict__ out, int R, int C) {
  __shared__ u16 tile[32][33];
  int bx = blockIdx.x, by = blockIdx.y;
  int tx = threadIdx.x & 31, ty = threadIdx.x >> 5;
#pragma unroll
  for (int k = 0; k < 4; ++k)
    tile[ty + k * 8][tx] = f2bf(in[(size_t)(by * 32 + ty + k * 8) * C + bx * 32 + tx]);
  __syncthreads();
#pragma unroll
  for (int k = 0; k < 4; ++k)
    out[(size_t)(bx * 32 + ty + k * 8) * R + by * 32 + tx] = tile[tx][ty + k * 8];
}

// combined bias (fp32 exact); z==0 (Q) scaled by SCALE*log2e
__global__ __launch_bounds__(256) void cbias3(const float* __restrict__ qw, const float* __restrict__ kw,
                                              const float* __restrict__ vw, const float* __restrict__ qkvb,
                                              const float* __restrict__ qb, const float* __restrict__ kb,
                                              const float* __restrict__ vb, float* __restrict__ out) {
  int z = blockIdx.y;
  const float* w = z == 0 ? qw : (z == 1 ? kw : vw);
  const float* ba = z == 0 ? qb : (z == 1 ? kb : vb);
  const float* bi = qkvb + z * 1024;
  int o = blockIdx.x * 4 + (threadIdx.x >> 6);
  int lane = threadIdx.x & 63;
  float s = 0.f;
  for (int m = lane; m < 1024; m += 64) s += w[o * 1024 + m] * bi[m];
#pragma unroll
  for (int d = 1; d < 64; d <<= 1) s += __shfl_xor(s, d);
  if (lane == 0) {
    float fin = s + ba[o];
    if (z == 0) fin *= kQScale;
    out[z * 1024 + o] = fin;
  }
}

// attn_mask -> bit-packed KEEP rows (2048 x 32 u64): bit = 1 where attn_mask != 1
__global__ __launch_bounds__(256) void pack_mask(const int* __restrict__ m, u64* __restrict__ pm) {
  int row = blockIdx.x;
  int wv = threadIdx.x >> 6, lane = threadIdx.x & 63;
#pragma unroll
  for (int i = 0; i < 8; ++i) {
    int word = wv * 8 + i;
    u64 b = __ballot(m[(size_t)row * 2048 + word * 64 + lane] == 0);
    if (lane == 0) pm[(size_t)row * 32 + word] = b;
  }
}

// ---------------- NT GEMM 128^2 (m97-style), for small/odd-shaped GEMMs ----------------
template <typename OUT_T, bool BIAS_PER_ROW>
__global__ __launch_bounds__(256, 2) void gemm_nt(const u16* __restrict__ A, int lda, long bsA,
                                                  const u16* __restrict__ B, int ldb, long bsB,
                                                  OUT_T* __restrict__ C, int ldc, long bsC,
                                                  const float* __restrict__ bias, long bsBias,
                                                  int NtilesN, int K, float scale_z0) {
  __shared__ __align__(16) u16 As[128 * 64];
  __shared__ __align__(16) u16 Bs[128 * 64];
  const int z = blockIdx.z;
  const float sc = (z == 0) ? scale_z0 : 1.f;
  A += (size_t)z * bsA; B += (size_t)z * bsB; C += (size_t)z * bsC;
  if (bias) bias += (size_t)z * bsBias;
  const int tm = blockIdx.x / NtilesN, tn = blockIdx.x % NtilesN;
  const int tid = threadIdx.x, lane = tid & 63, w = tid >> 6;
  const int wm = w >> 1, wn = w & 1;
  const int q = lane & 15, g = lane >> 4;
  f32x4 acc[4][4] = {};

  const u16* Ab = A + (size_t)(tm * 128 + (tid >> 3)) * lda + ((tid & 7) << 3);
  const u16* Bb = B + (size_t)(tn * 128 + (tid >> 3)) * ldb + ((tid & 7) << 3);
  char* AsW = (char*)As + (w << 10);
  char* BsW = (char*)Bs + (w << 10);

  for (int k0 = 0; k0 < K; k0 += 64) {
#pragma unroll
    for (int it = 0; it < 4; ++it) {
      g2lds16(Ab + (size_t)(it * 32) * lda + k0, AsW + it * 4096);
      g2lds16(Bb + (size_t)(it * 32) * ldb + k0, BsW + it * 4096);
    }
    __syncthreads();
#pragma unroll
    for (int kk = 0; kk < 2; ++kk) {
      s16x8 af[4], bf[4];
#pragma unroll
      for (int i = 0; i < 4; ++i)
        af[i] = *(const s16x8*)((const char*)As + (wm * 64 + i * 16 + q) * 128 + kk * 64 + g * 16);
#pragma unroll
      for (int i = 0; i < 4; ++i)
        bf[i] = *(const s16x8*)((const char*)Bs + (wn * 64 + i * 16 + q) * 128 + kk * 64 + g * 16);
#pragma unroll
      for (int mf = 0; mf < 4; ++mf)
#pragma unroll
        for (int nf = 0; nf < 4; ++nf) mfma16(acc[mf][nf], af[mf], bf[nf]);
    }
    __syncthreads();
  }
  asm volatile("s_nop 7\n\ts_nop 7");
#pragma unroll
  for (int mf = 0; mf < 4; ++mf)
#pragma unroll
    for (int nf = 0; nf < 4; ++nf) {
      const int row = tm * 128 + wm * 64 + mf * 16 + g * 4;
      const int col = tn * 128 + wn * 64 + nf * 16 + q;
      float bc = (!BIAS_PER_ROW && bias) ? bias[col] : 0.f;
#pragma unroll
      for (int r = 0; r < 4; ++r) {
        float v = acc[mf][nf][r] * sc;
        if (bias) v += BIAS_PER_ROW ? bias[row + r] : bc;
        if constexpr (sizeof(OUT_T) == 2)
          C[(size_t)(row + r) * ldc + col] = (OUT_T)f2bf(v);
        else
          C[(size_t)(row + r) * ldc + col] = (OUT_T)v;
      }
    }
}

// ---------------- 256^2 8-wave 4-phase GEMM (T2+T3+T4+T5), NT, bf16 out + col bias -------
// Wave (wm,wn) owns rows {wm*64..+63} u {128+wm*64..+63}, cols {wn*32..+31} u {128+wn*32..+31}
// so each phase's LDS reads touch exactly one A/B half-tile region.
// Stage schedule per kt: p0:A-h0(kt+1) p1:A-h1(kt+1) p2:B-h0(kt+2) p3:B-h1(kt+2); counted
// vmcnt(8) @p1-end guarantees A-h1(kt), vmcnt(6) @p3-end guarantees A-h0(kt+1)&B(kt+1).
__global__ __launch_bounds__(512, 1) void gemm256(const u16* __restrict__ A, int lda,
                                                  const u16* __restrict__ B, int ldb,
                                                  u16* __restrict__ C, int ldc,
                                                  const float* __restrict__ bias,
                                                  int K, int NtN) {
  __shared__ __align__(16) u16 Als[2][256 * 64];
  __shared__ __align__(16) u16 Bls[2][256 * 64];
  const int bid = blockIdx.x;
  const int cpx = gridDim.x >> 3;                      // grid % 8 == 0
  const int wgid = (bid & 7) * cpx + (bid >> 3);       // XCD-contiguous
  const int tm = wgid / NtN, tn = wgid % NtN;
  const int tid = threadIdx.x, lane = tid & 63, w = tid >> 6;
  const int wm = w >> 2, wn = w & 3;
  const int q = lane & 15, g = lane >> 4, qk = q & 7;
  const int nT = K >> 6;

  f32x4 acc[8][4] = {};
  s16x8 af[4][2], bf[4][2];

  // staging geometry: thread covers (row = tid>>3 [+64], chunk = tid&7), XOR-swizzled source
  const int srow = tid >> 3, sch = tid & 7;
  const int gcol = (sch ^ (srow & 7)) << 3;
  const u16* Abase = A + (size_t)(tm * 256 + srow) * lda + gcol;
  const u16* Bbase = B + (size_t)(tn * 256 + srow) * ldb + gcol;

  auto stageA = [&](int buf, int kt, int h) {
    const u16* s0 = Abase + (size_t)(h * 128) * lda + (kt << 6);
    char* d = (char*)&Als[buf][0] + h * 16384 + (w << 10);
    g2lds16(s0, d);
    g2lds16(s0 + (size_t)64 * lda, d + 8192);
  };
  auto stageB = [&](int buf, int kt, int h) {
    const u16* s0 = Bbase + (size_t)(h * 128) * ldb + (kt << 6);
    char* d = (char*)&Bls[buf][0] + h * 16384 + (w << 10);
    g2lds16(s0, d);
    g2lds16(s0 + (size_t)64 * ldb, d + 8192);
  };
  auto loadA = [&](const char* base, int mh) {
#pragma unroll
    for (int mf = 0; mf < 4; ++mf)
#pragma unroll
      for (int kk = 0; kk < 2; ++kk)
        af[mf][kk] = *(const s16x8*)(base + (mh * 128 + wm * 64 + mf * 16 + q) * 128 +
                                     ((((kk << 2) + g) ^ qk) << 4));
  };
  auto loadB = [&](const char* base, int nh) {
#pragma unroll
    for (int nf = 0; nf < 2; ++nf)
#pragma unroll
      for (int kk = 0; kk < 2; ++kk)
        bf[nh * 2 + nf][kk] = *(const s16x8*)(base + (nh * 128 + wn * 32 + nf * 16 + q) * 128 +
                                              ((((kk << 2) + g) ^ qk) << 4));
  };
  auto quad = [&](int mh, int nh) {
    __builtin_amdgcn_s_setprio(1);
#pragma unroll
    for (int mf = 0; mf < 4; ++mf)
#pragma unroll
      for (int nf = 0; nf < 2; ++nf)
#pragma unroll
        for (int kk = 0; kk < 2; ++kk)
          mfma16(acc[mh * 4 + mf][nh * 2 + nf], af[mf][kk], bf[nh * 2 + nf][kk]);
    __builtin_amdgcn_s_setprio(0);
  };

  // prologue: full kt0 + B halves of kt1
  stageA(0, 0, 0); stageA(0, 0, 1); stageB(0, 0, 0); stageB(0, 0, 1);
  const int kt1 = (1 < nT) ? 1 : 0;
  stageB(1, kt1, 0); stageB(1, kt1, 1);
  asm volatile("s_waitcnt vmcnt(4)" ::: "memory");
  BAR();

  for (int kt = 0; kt < nT; ++kt) {
    const int buf = kt & 1;
    const char* Ab = (const char*)&Als[buf][0];
    const char* Bb = (const char*)&Bls[buf][0];
    const int ktA = (kt + 1 < nT) ? kt + 1 : nT - 1;   // clamp keeps vmcnt counts uniform
    const int ktB = (kt + 2 < nT) ? kt + 2 : nT - 1;
    // p0
    loadA(Ab, 0); loadB(Bb, 0);
    stageA(buf ^ 1, ktA, 0);
    BAR();
    quad(0, 0);
    BAR();
    // p1
    loadB(Bb, 1);
    stageA(buf ^ 1, ktA, 1);
    BAR();
    quad(0, 1);
    asm volatile("s_waitcnt vmcnt(8)" ::: "memory");
    BAR();
    // p2
    loadA(Ab, 1);
    stageB(buf, ktB, 0);
    BAR();
    quad(1, 0);
    BAR();
    // p3
    stageB(buf, ktB, 1);
    BAR();
    quad(1, 1);
    asm volatile("s_waitcnt vmcnt(6)" ::: "memory");
    BAR();
  }

  asm volatile("s_nop 7\n\ts_nop 7");
#pragma unroll
  for (int mf = 0; mf < 8; ++mf) {
    const int row = tm * 256 + (mf >> 2) * 128 + wm * 64 + (mf & 3) * 16 + g * 4;
#pragma unroll
    for (int nf = 0; nf < 4; ++nf) {
      const int col = tn * 256 + (nf >> 1) * 128 + wn * 32 + (nf & 1) * 16 + q;
      const float bc = bias[col];
#pragma unroll
      for (int r = 0; r < 4; ++r)
        C[(size_t)(row + r) * ldc + col] = f2bf(acc[mf][nf][r] + bc);
    }
  }
}

// ---------------- flash attention: swapped QK^T (32x32), in-register P, MFMA l-sum -------
// Q (pre-scaled by SCALE*log2e), K: rows = token, stride ldq, head h at cols [h*128,+128).
// Vt: (1024 x 8192) bf16 [d][token]. Softmax unnormalized: P = exp2(s) (factor cancels).
__global__ __launch_bounds__(256, 2) void attn_fwd(const u16* __restrict__ Qb, const u16* __restrict__ Kb,
                                                   int ldq, const u16* __restrict__ Vt,
                                                   const u64* __restrict__ pmask,
                                                   u16* __restrict__ Ob) {
  __shared__ __align__(16) char K_lds[2 * 16384];  // [64 kv][128 d], 16B-chunk XOR (kv&15)
  __shared__ __align__(16) char V_lds[2 * 16384];  // [128 d][64 kv], 16B-chunk XOR (d&7)
  const int n = blockIdx.x;
  const int slot = n >> 3;
  const int grp = (n & 7) * 4 + (slot >> 4);
  const int qt = slot & 15;
  const int h = grp & 7, b = grp >> 3;
  const int tid = threadIdx.x, w = tid >> 6, lane = tid & 63;
  const int ql = lane & 31;
  const int hi = lane >> 5;
  const int q0 = qt * 128;

  s16x8 qf[8];
  const u16* qrow = Qb + (size_t)(b * 2048 + q0 + w * 32 + ql) * ldq + h * 128 + 8 * hi;
#pragma unroll
  for (int kd = 0; kd < 8; ++kd) qf[kd] = *(const s16x8*)(qrow + 16 * kd);

  u32x4 ov = {0x3F803F80u, 0x3F803F80u, 0x3F803F80u, 0x3F803F80u};
  const s16x8 ones = __builtin_bit_cast(s16x8, ov);

  f32x16 oacc[4] = {};   // dt: O[q=crow(reg,hi)][d = dt*32+ql]
  f32x16 lacc = {};      // l[q=crow(reg,hi)] in every column

  const int ksr = tid >> 4, ksc = tid & 15;  // K staging
  const int vsr = tid >> 3, vsc = tid & 7;   // V staging
  const int sw = ql & 15;                    // K read swizzle key

  auto stageKV = [&](int buf, int s2) {
    const int kv0 = s2 * 64;
    char* kb = K_lds + buf * 16384 + (w << 10);
    char* vb = V_lds + buf * 16384 + (w << 10);
#pragma unroll
    for (int it = 0; it < 4; ++it) {
      int kr = it * 16 + ksr;
      g2lds16(Kb + (size_t)(b * 2048 + kv0 + kr) * ldq + h * 128 + ((ksc ^ (kr & 15)) << 3),
              kb + it * 4096);
      int vr = it * 32 + vsr;
      g2lds16(Vt + (size_t)(h * 128 + vr) * 8192 + b * 2048 + kv0 + ((vsc ^ (vr & 7)) << 3),
              vb + it * 4096);
    }
  };

  stageKV(0, 0);
  __syncthreads();

  for (int s = 0; s < 32; ++s) {
    const int cur = s & 1;
    if (s + 1 < 32) stageKV(cur ^ 1, s + 1);
    const char* Kc = K_lds + cur * 16384;
    const char* Vc = V_lds + cur * 16384;

    u64 pw = pmask[(size_t)(q0 + w * 32 + ql) * 32 + s];   // KEEP bits

    // S^T[kv][q] = K · Q^T
    f32x16 sacc0, sacc1;
    __builtin_amdgcn_s_setprio(1);
#pragma unroll
    for (int kd = 0; kd < 8; ++kd) {
      int c = (2 * kd + hi) ^ sw;
      s16x8 kf0 = *(const s16x8*)(Kc + ql * 256 + (c << 4));
      s16x8 kf1 = *(const s16x8*)(Kc + (32 + ql) * 256 + (c << 4));
      if (kd == 0) { sacc0 = mfma32_z(kf0, qf[0]); sacc1 = mfma32_z(kf1, qf[0]); }
      else         { mfma32(sacc0, kf0, qf[kd]);   mfma32(sacc1, kf1, qf[kd]); }
    }
    __builtin_amdgcn_s_setprio(0);
    asm volatile("s_nop 7\n\ts_nop 7");

    // in-register softmax: P = exp2(s), zeroed where keep-bit==0 (bfe_i32 + and)
    u32 Wp[8][2];
#pragma unroll
    for (int nt = 0; nt < 2; ++nt) {
      u32 halfm = (u32)(pw >> (32 * nt + 4 * hi));
#pragma unroll
      for (int t = 0; t < 4; ++t) {
        float e[4];
#pragma unroll
        for (int j = 0; j < 4; ++j) {
          float ev = fexp2(nt == 0 ? sacc0[4 * t + j] : sacc1[4 * t + j]);
          int km;
          asm("v_bfe_i32 %0, %1, %2, 1" : "=v"(km) : "v"(halfm), "n"(8 * t + j));
          e[j] = __uint_as_float(__float_as_uint(ev) & (u32)km);
        }
        Wp[nt * 4 + t][0] = cvtpk(e[0], e[1]);
        Wp[nt * 4 + t][1] = cvtpk(e[2], e[3]);
      }
    }

    // exchange odd/even groups with lane^32, assemble PV A-frags pa[ks]
    s16x8 pa[4];
#pragma unroll
    for (int ks = 0; ks < 4; ++ks) {
      u32 s0 = hi ? Wp[2 * ks][0] : Wp[2 * ks + 1][0];
      u32 s1 = hi ? Wp[2 * ks][1] : Wp[2 * ks + 1][1];
      u32 r0 = (u32)__shfl_xor((int)s0, 32);
      u32 r1 = (u32)__shfl_xor((int)s1, 32);
      u32 o0 = hi ? Wp[2 * ks + 1][0] : Wp[2 * ks][0];
      u32 o1 = hi ? Wp[2 * ks + 1][1] : Wp[2 * ks][1];
      u32x4 wv;
      wv.x = hi ? r0 : o0;
      wv.y = hi ? r1 : o1;
      wv.z = hi ? o0 : r0;
      wv.w = hi ? o1 : r1;
      pa[ks] = __builtin_bit_cast(s16x8, wv);
    }
    asm volatile("s_nop 3");

    // O += P V ; l += P · 1  (row-sum on the MFMA pipe)
    __builtin_amdgcn_s_setprio(1);
#pragma unroll
    for (int ks = 0; ks < 4; ++ks) {
#pragma unroll
      for (int dt = 0; dt < 4; ++dt) {
        int vrow = dt * 32 + ql;
        s16x8 vf = *(const s16x8*)(Vc + vrow * 128 + ((((2 * ks + hi)) ^ (vrow & 7)) << 4));
        mfma32(oacc[dt], pa[ks], vf);
      }
      mfma32(lacc, pa[ks], ones);
    }
    __builtin_amdgcn_s_setprio(0);
    __syncthreads();
  }

  asm volatile("s_nop 7\n\ts_nop 7");
#pragma unroll
  for (int dt = 0; dt < 4; ++dt)
#pragma unroll
    for (int reg = 0; reg < 16; ++reg) {
      int qr = (reg & 3) + 8 * (reg >> 2) + 4 * hi;
      size_t trow = (size_t)(b * 2048 + q0 + w * 32 + qr);
      Ob[trow * 1024 + h * 128 + dt * 32 + ql] = f2bf(oacc[dt][reg] / lacc[reg]);
    }
}

// ---------------- launcher ----------------
extern "C" void kernel_launch(void* const* d_in, const int* in_sizes, int n_in,
                              void* d_out, int out_size, void* d_ws, size_t ws_size,
                              hipStream_t stream) {
  (void)in_sizes; (void)n_in; (void)out_size; (void)ws_size;
  const float* x    = (const float*)d_in[0];
  const int*   am   = (const int*)d_in[1];
  const float* qkvw = (const float*)d_in[2];
  const float* qkvb = (const float*)d_in[3];
  const float* qw   = (const float*)d_in[4];
  const float* qb   = (const float*)d_in[5];
  const float* kw   = (const float*)d_in[6];
  const float* kb   = (const float*)d_in[7];
  const float* vw   = (const float*)d_in[8];
  const float* vb   = (const float*)d_in[9];
  const float* ow   = (const float*)d_in[10];
  const float* ob   = (const float*)d_in[11];

  char* p = (char*)d_ws;
  auto take = [&](size_t n) { char* r = p; p += (n + 255) & ~(size_t)255; return r; };
  u16* xb    = (u16*)take(8192ull * 1024 * 2);        // also reused as attention output
  u16* qkvwT = (u16*)take(1024ull * 3072 * 2);
  u16* wb4   = (u16*)take(4ull * 1048576 * 2);        // qwb,kwb,vwb,owb
  u16* comb3 = (u16*)take(3ull * 1048576 * 2);        // comb_q (pre-scaled), comb_k, comb_v
  float* cb3 = (float*)take(3ull * 1024 * 4);
  u16* QK2   = (u16*)take(8192ull * 2048 * 2);        // fused [Q|K] (8192 x 2048)
  u16* V2t   = (u16*)take(8192ull * 1024 * 2);
  u64* pm    = (u64*)take(2048ull * 32 * 8);
  u16* Obuf  = xb;                                    // alias: xb dead after projections

  cvt_f32_bf16<<<8192, 256, 0, stream>>>(x, xb, 8192 * 1024);
  cvt4<<<dim3(1024, 4), 256, 0, stream>>>(qw, kw, vw, ow, wb4);
  transpose_f32_bf16<<<dim3(32, 96), 256, 0, stream>>>(qkvw, qkvwT, 3072, 1024);
  cbias3<<<dim3(256, 3), 256, 0, stream>>>(qw, kw, vw, qkvb, qb, kb, vb, cb3);

  // combined weights: comb_z[o][i] = sum_m W_z[o][m] * qkv_w[z*1024+m][i]; z==0 scaled
  gemm_nt<u16, false><<<dim3(64, 1, 3), 256, 0, stream>>>(
      wb4, 1024, 1048576, qkvwT, 3072, 1024, comb3, 1024, 1048576, nullptr, 0, 8, 1024, kQScale);
  // fused Q|K projection: C[8192][2048] = xb @ [comb_q; comb_k]^T + [cb_q; cb_k]
  gemm256<<<256, 512, 0, stream>>>(xb, 1024, comb3, 1024, QK2, 2048, cb3, 1024, 8);
  // V transposed: V2t[o][t] = comb_v[o]·x[t] + cb_v[o]  (bias per row)
  gemm_nt<u16, true><<<dim3(512, 1, 1), 256, 0, stream>>>(
      comb3 + 2 * 1048576, 1024, 0, xb, 1024, 0, V2t, 8192, 0, cb3 + 2048, 0, 64, 1024, 1.f);

  pack_mask<<<2048, 256, 0, stream>>>(am, pm);
  attn_fwd<<<512, 256, 0, stream>>>(QK2, QK2 + 1024, 2048, V2t, pm, Obuf);

  // out = O @ out_w^T + out_b  (fp32 output)
  gemm_nt<float, false><<<dim3(512, 1, 1), 256, 0, stream>>>(
      Obuf, 1024, 0, wb4 + 3 * 1048576, 1024, 0, (float*)d_out, 1024, 0, ob, 0, 8, 1024, 1.f);
}

// Round 6
// 243.667 us; speedup vs baseline: 1.4091x; 1.0048x over previous
//
#include <hip/hip_runtime.h>
#include <stdint.h>

typedef unsigned short u16;
typedef unsigned int u32;
typedef unsigned long long u64;
using f32x4 = __attribute__((ext_vector_type(4))) float;
using f32x16 = __attribute__((ext_vector_type(16))) float;
using s16x8 = __attribute__((ext_vector_type(8))) short;
using u16x4 = __attribute__((ext_vector_type(4))) unsigned short;
using u32x4 = __attribute__((ext_vector_type(4))) u32;

static constexpr float kQScale = (float)(0.08838834764831845 * 1.4426950408889634);  // SCALE*log2(e)

__device__ __forceinline__ u16 f2bf(float f) {
  uint32_t u = __float_as_uint(f);
  u += 0x7fffu + ((u >> 16) & 1u);   // RNE
  return (u16)(u >> 16);
}

__device__ __forceinline__ float fexp2(float x) {
#if __has_builtin(__builtin_amdgcn_exp2f)
  return __builtin_amdgcn_exp2f(x);
#else
  return exp2f(x);
#endif
}

__device__ __forceinline__ u32 cvtpk(float lo, float hi) {
  u32 r;
  asm("v_cvt_pk_bf16_f32 %0, %1, %2" : "=v"(r) : "v"(lo), "v"(hi));
  return r;
}

// 16x16x32 bf16 MFMA (D=C tied): C/D col=lane&15, row=4*(lane>>4)+reg [m89/m91].
__device__ __forceinline__ void mfma16(f32x4& d, s16x8 a, s16x8 b) {
  asm volatile("v_mfma_f32_16x16x32_bf16 %0, %1, %2, %0" : "+v"(d) : "v"(a), "v"(b));
}
// 32x32x16 bf16 MFMA: A row=lane&31,k=8*(lane>>5)+j; B col=lane&31;
// C/D col=lane&31, row=(reg&3)+8*(reg>>2)+4*(lane>>5) [m74/m101].
__device__ __forceinline__ void mfma32(f32x16& d, s16x8 a, s16x8 b) {
  asm volatile("v_mfma_f32_32x32x16_bf16 %0, %1, %2, %0" : "+v"(d) : "v"(a), "v"(b));
}
__device__ __forceinline__ f32x16 mfma32_z(s16x8 a, s16x8 b) {
  f32x16 d;
  asm volatile("v_mfma_f32_32x32x16_bf16 %0, %1, %2, 0" : "=&v"(d) : "v"(a), "v"(b));
  return d;
}

// async global->LDS, 16B per lane; LDS dest = wave-uniform base + lane*16 (m104).
__device__ __forceinline__ void g2lds16(const void* g, void* l) {
  __builtin_amdgcn_global_load_lds(
      (__attribute__((address_space(1))) void*)(uintptr_t)g,
      (__attribute__((address_space(3))) void*)(uint32_t)(uintptr_t)l, 16, 0, 0);
}

#define BAR() asm volatile("s_barrier" ::: "memory")

// ---------------- elementwise converts ----------------
__global__ __launch_bounds__(256) void cvt_f32_bf16(const float* __restrict__ in,
                                                    u16* __restrict__ out, int n) {
  int i = (blockIdx.x * 256 + threadIdx.x) * 4;
  if (i + 3 < n) {
    f32x4 v = *(const f32x4*)(in + i);
    u16x4 o = {f2bf(v.x), f2bf(v.y), f2bf(v.z), f2bf(v.w)};
    *(u16x4*)(out + i) = o;
  }
}

__global__ __launch_bounds__(256) void cvt4(const float* __restrict__ a, const float* __restrict__ b,
                                            const float* __restrict__ c, const float* __restrict__ d,
                                            u16* __restrict__ out) {
  int z = blockIdx.y;
  const float* in = z == 0 ? a : z == 1 ? b : z == 2 ? c : d;
  int i = (blockIdx.x * 256 + threadIdx.x) * 4;
  f32x4 v = *(const f32x4*)(in + i);
  u16x4 o = {f2bf(v.x), f2bf(v.y), f2bf(v.z), f2bf(v.w)};
  *(u16x4*)(out + (size_t)z * 1048576 + i) = o;
}

// qkv_w (R=3072 x C=1024 f32) -> qkv_wT (C x R bf16)
__global__ __launch_bounds__(256) void transpose_f32_bf16(const float* __restrict__ in,
                                                          u16* __restrict__ out, int R, int C) {
  __shared__ u16 tile[32][33];
  int bx = blockIdx.x, by = blockIdx.y;
  int tx = threadIdx.x & 31, ty = threadIdx.x >> 5;
#pragma unroll
  for (int k = 0; k < 4; ++k)
    tile[ty + k * 8][tx] = f2bf(in[(size_t)(by * 32 + ty + k * 8) * C + bx * 32 + tx]);
  __syncthreads();
#pragma unroll
  for (int k = 0; k < 4; ++k)
    out[(size_t)(bx * 32 + ty + k * 8) * R + by * 32 + tx] = tile[tx][ty + k * 8];
}

// combined bias (fp32 exact); z==0 (Q) scaled by SCALE*log2e
__global__ __launch_bounds__(256) void cbias3(const float* __restrict__ qw, const float* __restrict__ kw,
                                              const float* __restrict__ vw, const float* __restrict__ qkvb,
                                              const float* __restrict__ qb, const float* __restrict__ kb,
                                              const float* __restrict__ vb, float* __restrict__ out) {
  int z = blockIdx.y;
  const float* w = z == 0 ? qw : (z == 1 ? kw : vw);
  const float* ba = z == 0 ? qb : (z == 1 ? kb : vb);
  const float* bi = qkvb + z * 1024;
  int o = blockIdx.x * 4 + (threadIdx.x >> 6);
  int lane = threadIdx.x & 63;
  float s = 0.f;
  for (int m = lane; m < 1024; m += 64) s += w[o * 1024 + m] * bi[m];
#pragma unroll
  for (int d = 1; d < 64; d <<= 1) s += __shfl_xor(s, d);
  if (lane == 0) {
    float fin = s + ba[o];
    if (z == 0) fin *= kQScale;
    out[z * 1024 + o] = fin;
  }
}

// attn_mask -> bit-packed KEEP rows (2048 x 32 u64): bit = 1 where attn_mask != 1
__global__ __launch_bounds__(256) void pack_mask(const int* __restrict__ m, u64* __restrict__ pm) {
  int row = blockIdx.x;
  int wv = threadIdx.x >> 6, lane = threadIdx.x & 63;
#pragma unroll
  for (int i = 0; i < 8; ++i) {
    int word = wv * 8 + i;
    u64 b = __ballot(m[(size_t)row * 2048 + word * 64 + lane] == 0);
    if (lane == 0) pm[(size_t)row * 32 + word] = b;
  }
}

// ---------------- NT GEMM 128^2 (m97-style), for small/odd-shaped GEMMs ----------------
template <typename OUT_T, bool BIAS_PER_ROW>
__global__ __launch_bounds__(256, 2) void gemm_nt(const u16* __restrict__ A, int lda, long bsA,
                                                  const u16* __restrict__ B, int ldb, long bsB,
                                                  OUT_T* __restrict__ C, int ldc, long bsC,
                                                  const float* __restrict__ bias, long bsBias,
                                                  int NtilesN, int K, float scale_z0) {
  __shared__ __align__(16) u16 As[128 * 64];
  __shared__ __align__(16) u16 Bs[128 * 64];
  const int z = blockIdx.z;
  const float sc = (z == 0) ? scale_z0 : 1.f;
  A += (size_t)z * bsA; B += (size_t)z * bsB; C += (size_t)z * bsC;
  if (bias) bias += (size_t)z * bsBias;
  const int tm = blockIdx.x / NtilesN, tn = blockIdx.x % NtilesN;
  const int tid = threadIdx.x, lane = tid & 63, w = tid >> 6;
  const int wm = w >> 1, wn = w & 1;
  const int q = lane & 15, g = lane >> 4;
  f32x4 acc[4][4] = {};

  const u16* Ab = A + (size_t)(tm * 128 + (tid >> 3)) * lda + ((tid & 7) << 3);
  const u16* Bb = B + (size_t)(tn * 128 + (tid >> 3)) * ldb + ((tid & 7) << 3);
  char* AsW = (char*)As + (w << 10);
  char* BsW = (char*)Bs + (w << 10);

  for (int k0 = 0; k0 < K; k0 += 64) {
#pragma unroll
    for (int it = 0; it < 4; ++it) {
      g2lds16(Ab + (size_t)(it * 32) * lda + k0, AsW + it * 4096);
      g2lds16(Bb + (size_t)(it * 32) * ldb + k0, BsW + it * 4096);
    }
    __syncthreads();
#pragma unroll
    for (int kk = 0; kk < 2; ++kk) {
      s16x8 af[4], bf[4];
#pragma unroll
      for (int i = 0; i < 4; ++i)
        af[i] = *(const s16x8*)((const char*)As + (wm * 64 + i * 16 + q) * 128 + kk * 64 + g * 16);
#pragma unroll
      for (int i = 0; i < 4; ++i)
        bf[i] = *(const s16x8*)((const char*)Bs + (wn * 64 + i * 16 + q) * 128 + kk * 64 + g * 16);
#pragma unroll
      for (int mf = 0; mf < 4; ++mf)
#pragma unroll
        for (int nf = 0; nf < 4; ++nf) mfma16(acc[mf][nf], af[mf], bf[nf]);
    }
    __syncthreads();
  }
  asm volatile("s_nop 7\n\ts_nop 7");
#pragma unroll
  for (int mf = 0; mf < 4; ++mf)
#pragma unroll
    for (int nf = 0; nf < 4; ++nf) {
      const int row = tm * 128 + wm * 64 + mf * 16 + g * 4;
      const int col = tn * 128 + wn * 64 + nf * 16 + q;
      float bc = (!BIAS_PER_ROW && bias) ? bias[col] : 0.f;
#pragma unroll
      for (int r = 0; r < 4; ++r) {
        float v = acc[mf][nf][r] * sc;
        if (bias) v += BIAS_PER_ROW ? bias[row + r] : bc;
        if constexpr (sizeof(OUT_T) == 2)
          C[(size_t)(row + r) * ldc + col] = (OUT_T)f2bf(v);
        else
          C[(size_t)(row + r) * ldc + col] = (OUT_T)v;
      }
    }
}

// ---------------- 256^2 8-wave 4-phase GEMM (T2+T3+T4+T5), NT, bf16 out + col bias -------
__global__ __launch_bounds__(512, 1) void gemm256(const u16* __restrict__ A, int lda,
                                                  const u16* __restrict__ B, int ldb,
                                                  u16* __restrict__ C, int ldc,
                                                  const float* __restrict__ bias,
                                                  int K, int NtN) {
  __shared__ __align__(16) u16 Als[2][256 * 64];
  __shared__ __align__(16) u16 Bls[2][256 * 64];
  const int bid = blockIdx.x;
  const int cpx = gridDim.x >> 3;                      // grid % 8 == 0
  const int wgid = (bid & 7) * cpx + (bid >> 3);       // XCD-contiguous
  const int tm = wgid / NtN, tn = wgid % NtN;
  const int tid = threadIdx.x, lane = tid & 63, w = tid >> 6;
  const int wm = w >> 2, wn = w & 3;
  const int q = lane & 15, g = lane >> 4, qk = q & 7;
  const int nT = K >> 6;

  f32x4 acc[8][4] = {};
  s16x8 af[4][2], bf[4][2];

  const int srow = tid >> 3, sch = tid & 7;
  const int gcol = (sch ^ (srow & 7)) << 3;
  const u16* Abase = A + (size_t)(tm * 256 + srow) * lda + gcol;
  const u16* Bbase = B + (size_t)(tn * 256 + srow) * ldb + gcol;

  auto stageA = [&](int buf, int kt, int h) {
    const u16* s0 = Abase + (size_t)(h * 128) * lda + (kt << 6);
    char* d = (char*)&Als[buf][0] + h * 16384 + (w << 10);
    g2lds16(s0, d);
    g2lds16(s0 + (size_t)64 * lda, d + 8192);
  };
  auto stageB = [&](int buf, int kt, int h) {
    const u16* s0 = Bbase + (size_t)(h * 128) * ldb + (kt << 6);
    char* d = (char*)&Bls[buf][0] + h * 16384 + (w << 10);
    g2lds16(s0, d);
    g2lds16(s0 + (size_t)64 * ldb, d + 8192);
  };
  auto loadA = [&](const char* base, int mh) {
#pragma unroll
    for (int mf = 0; mf < 4; ++mf)
#pragma unroll
      for (int kk = 0; kk < 2; ++kk)
        af[mf][kk] = *(const s16x8*)(base + (mh * 128 + wm * 64 + mf * 16 + q) * 128 +
                                     ((((kk << 2) + g) ^ qk) << 4));
  };
  auto loadB = [&](const char* base, int nh) {
#pragma unroll
    for (int nf = 0; nf < 2; ++nf)
#pragma unroll
      for (int kk = 0; kk < 2; ++kk)
        bf[nh * 2 + nf][kk] = *(const s16x8*)(base + (nh * 128 + wn * 32 + nf * 16 + q) * 128 +
                                              ((((kk << 2) + g) ^ qk) << 4));
  };
  auto quad = [&](int mh, int nh) {
    __builtin_amdgcn_s_setprio(1);
#pragma unroll
    for (int mf = 0; mf < 4; ++mf)
#pragma unroll
      for (int nf = 0; nf < 2; ++nf)
#pragma unroll
        for (int kk = 0; kk < 2; ++kk)
          mfma16(acc[mh * 4 + mf][nh * 2 + nf], af[mf][kk], bf[nh * 2 + nf][kk]);
    __builtin_amdgcn_s_setprio(0);
  };

  stageA(0, 0, 0); stageA(0, 0, 1); stageB(0, 0, 0); stageB(0, 0, 1);
  const int kt1 = (1 < nT) ? 1 : 0;
  stageB(1, kt1, 0); stageB(1, kt1, 1);
  asm volatile("s_waitcnt vmcnt(4)" ::: "memory");
  BAR();

  for (int kt = 0; kt < nT; ++kt) {
    const int buf = kt & 1;
    const char* Ab = (const char*)&Als[buf][0];
    const char* Bb = (const char*)&Bls[buf][0];
    const int ktA = (kt + 1 < nT) ? kt + 1 : nT - 1;
    const int ktB = (kt + 2 < nT) ? kt + 2 : nT - 1;
    loadA(Ab, 0); loadB(Bb, 0);
    stageA(buf ^ 1, ktA, 0);
    BAR();
    quad(0, 0);
    BAR();
    loadB(Bb, 1);
    stageA(buf ^ 1, ktA, 1);
    BAR();
    quad(0, 1);
    asm volatile("s_waitcnt vmcnt(8)" ::: "memory");
    BAR();
    loadA(Ab, 1);
    stageB(buf, ktB, 0);
    BAR();
    quad(1, 0);
    BAR();
    stageB(buf, ktB, 1);
    BAR();
    quad(1, 1);
    asm volatile("s_waitcnt vmcnt(6)" ::: "memory");
    BAR();
  }

  asm volatile("s_nop 7\n\ts_nop 7");
#pragma unroll
  for (int mf = 0; mf < 8; ++mf) {
    const int row = tm * 256 + (mf >> 2) * 128 + wm * 64 + (mf & 3) * 16 + g * 4;
#pragma unroll
    for (int nf = 0; nf < 4; ++nf) {
      const int col = tn * 256 + (nf >> 1) * 128 + wn * 32 + (nf & 1) * 16 + q;
      const float bc = bias[col];
#pragma unroll
      for (int r = 0; r < 4; ++r)
        C[(size_t)(row + r) * ldc + col] = f2bf(acc[mf][nf][r] + bc);
    }
  }
}

// ---------------- flash attention: pipelined QK(s+1) ∥ softmax(s), in-register P ---------
// Q (pre-scaled by SCALE*log2e), K: rows = token, stride ldq, head h at cols [h*128,+128).
// Vt: (1024 x 8192) bf16 [d][token]. Unnormalized softmax P = exp2(s); l via ones-MFMA.
// Staging 2 tiles ahead: K 2-buf, V 3-buf; counted vmcnt(4) + raw barrier (no drain-0).
__global__ __launch_bounds__(256, 2) void attn_fwd(const u16* __restrict__ Qb, const u16* __restrict__ Kb,
                                                   int ldq, const u16* __restrict__ Vt,
                                                   const u64* __restrict__ pmask,
                                                   u16* __restrict__ Ob) {
  __shared__ __align__(16) char K_lds[2][16384];  // [64 kv][128 d], 16B-chunk XOR (kv&15)
  __shared__ __align__(16) char V_lds[3][16384];  // [128 d][64 kv], 16B-chunk XOR (d&7)
  const int n = blockIdx.x;
  const int slot = n >> 3;
  const int grp = (n & 7) * 4 + (slot >> 4);
  const int qt = slot & 15;
  const int h = grp & 7, b = grp >> 3;
  const int tid = threadIdx.x, w = tid >> 6, lane = tid & 63;
  const int ql = lane & 31;
  const int hi = lane >> 5;
  const int q0 = qt * 128;

  s16x8 qf[8];
  const u16* qrow = Qb + (size_t)(b * 2048 + q0 + w * 32 + ql) * ldq + h * 128 + 8 * hi;
#pragma unroll
  for (int kd = 0; kd < 8; ++kd) qf[kd] = *(const s16x8*)(qrow + 16 * kd);

  u32x4 ov = {0x3F803F80u, 0x3F803F80u, 0x3F803F80u, 0x3F803F80u};
  const s16x8 ones = __builtin_bit_cast(s16x8, ov);

  f32x16 oacc[4] = {};   // dt: O[q=crow(reg,hi)][d = dt*32+ql]
  f32x16 lacc = {};      // l[q=crow(reg,hi)] in every column

  const int ksr = tid >> 4, ksc = tid & 15;  // K staging
  const int vsr = tid >> 3, vsc = tid & 7;   // V staging
  const int sw = ql & 15;                    // K read swizzle key
  const u64* pmrow = pmask + (size_t)(q0 + w * 32 + ql) * 32;

  auto stageK = [&](int buf, int s2) {
    const int kv0 = s2 * 64;
    char* kb = K_lds[buf] + (w << 10);
#pragma unroll
    for (int it = 0; it < 4; ++it) {
      int kr = it * 16 + ksr;
      g2lds16(Kb + (size_t)(b * 2048 + kv0 + kr) * ldq + h * 128 + ((ksc ^ (kr & 15)) << 3),
              kb + it * 4096);
    }
  };
  auto stageV = [&](int buf, int s2) {
    const int kv0 = s2 * 64;
    char* vb = V_lds[buf] + (w << 10);
#pragma unroll
    for (int it = 0; it < 4; ++it) {
      int vr = it * 32 + vsr;
      g2lds16(Vt + (size_t)(h * 128 + vr) * 8192 + b * 2048 + kv0 + ((vsc ^ (vr & 7)) << 3),
              vb + it * 4096);
    }
  };
  auto qk = [&](f32x16& d0, f32x16& d1, int kbuf) {
    const char* Kc = K_lds[kbuf];
#pragma unroll
    for (int kd = 0; kd < 8; ++kd) {
      int c = (2 * kd + hi) ^ sw;
      s16x8 kf0 = *(const s16x8*)(Kc + ql * 256 + (c << 4));
      s16x8 kf1 = *(const s16x8*)(Kc + (32 + ql) * 256 + (c << 4));
      if (kd == 0) { d0 = mfma32_z(kf0, qf[0]); d1 = mfma32_z(kf1, qf[0]); }
      else         { mfma32(d0, kf0, qf[kd]);   mfma32(d1, kf1, qf[kd]); }
    }
  };

  // body: stage(s+2), issue QK(s+1) -> (n0,n1), softmax(s) from (c0,c1), PV(s)
  auto body = [&](f32x16& c0, f32x16& c1, f32x16& n0, f32x16& n1, int s, int vbR, int vbW) {
    u64 pw = pmrow[s];                         // KEEP bits
    const int sc2 = (s + 2 < 32) ? s + 2 : 31; // clamped stages only overwrite dead bufs
    stageK(s & 1, sc2);
    stageV(vbW, sc2);
    if (s + 1 < 32) qk(n0, n1, (s + 1) & 1);   // MFMA pipe fills; VALU below overlaps
    const char* Vc = V_lds[vbR];
    s16x8 pa[2];
#pragma unroll
    for (int half = 0; half < 2; ++half) {
      u32 halfm = (u32)(pw >> (32 * half + 4 * hi));
      u32 Wp[4][2];
#pragma unroll
      for (int t = 0; t < 4; ++t) {
        float e[4];
#pragma unroll
        for (int j = 0; j < 4; ++j) {
          float ev = fexp2(half == 0 ? c0[4 * t + j] : c1[4 * t + j]);
          int km;
          asm("v_bfe_i32 %0, %1, %2, 1" : "=v"(km) : "v"(halfm), "n"(8 * t + j));
          e[j] = __uint_as_float(__float_as_uint(ev) & (u32)km);
        }
        Wp[t][0] = cvtpk(e[0], e[1]);
        Wp[t][1] = cvtpk(e[2], e[3]);
      }
#pragma unroll
      for (int kq = 0; kq < 2; ++kq) {
        u32 s0 = hi ? Wp[2 * kq][0] : Wp[2 * kq + 1][0];
        u32 s1 = hi ? Wp[2 * kq][1] : Wp[2 * kq + 1][1];
        u32 r0 = (u32)__shfl_xor((int)s0, 32);
        u32 r1 = (u32)__shfl_xor((int)s1, 32);
        u32 o0 = hi ? Wp[2 * kq + 1][0] : Wp[2 * kq][0];
        u32 o1 = hi ? Wp[2 * kq + 1][1] : Wp[2 * kq][1];
        u32x4 wv;
        wv.x = hi ? r0 : o0;
        wv.y = hi ? r1 : o1;
        wv.z = hi ? o0 : r0;
        wv.w = hi ? o1 : r1;
        pa[kq] = __builtin_bit_cast(s16x8, wv);
      }
      asm volatile("s_nop 3");   // VALU->MFMA SrcA margin
      __builtin_amdgcn_s_setprio(1);
#pragma unroll
      for (int kq = 0; kq < 2; ++kq) {
        const int ks = 2 * half + kq;
#pragma unroll
        for (int dt = 0; dt < 4; ++dt) {
          int vrow = dt * 32 + ql;
          s16x8 vf = *(const s16x8*)(Vc + vrow * 128 + (((2 * ks + hi) ^ (vrow & 7)) << 4));
          mfma32(oacc[dt], pa[kq], vf);
        }
        mfma32(lacc, pa[kq], ones);
      }
      __builtin_amdgcn_s_setprio(0);
    }
    asm volatile("s_waitcnt vmcnt(4)" ::: "memory");  // all but V(s+2) landed
    BAR();
  };

  // prologue: KV(0), KV(1); K0/V0/K1 landed; QK(0)
  stageK(0, 0); stageV(0, 0); stageK(1, 1); stageV(1, 1);
  asm volatile("s_waitcnt vmcnt(4)" ::: "memory");
  BAR();
  f32x16 sA0, sA1, sB0, sB1;
  qk(sA0, sA1, 0);
  BAR();   // QK(0) reads consumed; iter-0 staging may now overwrite K buf0

  int vb = 0;                                  // vb = s % 3
  for (int s2 = 0; s2 < 16; ++s2) {
    const int s = 2 * s2;
    const int vb1 = (vb + 1 == 3) ? 0 : vb + 1;
    const int vb2 = (vb + 2 >= 3) ? vb - 1 : vb + 2;
    body(sA0, sA1, sB0, sB1, s, vb, vb2);      // reads V(s)@vb, stages V(s+2)@vb2
    body(sB0, sB1, sA0, sA1, s + 1, vb1, vb);  // reads V(s+1)@vb1, stages V(s+3)@vb
    vb = vb2;
  }

  asm volatile("s_nop 7\n\ts_nop 7");
#pragma unroll
  for (int dt = 0; dt < 4; ++dt)
#pragma unroll
    for (int reg = 0; reg < 16; ++reg) {
      int qr = (reg & 3) + 8 * (reg >> 2) + 4 * hi;
      size_t trow = (size_t)(b * 2048 + q0 + w * 32 + qr);
      Ob[trow * 1024 + h * 128 + dt * 32 + ql] = f2bf(oacc[dt][reg] / lacc[reg]);
    }
}

// ---------------- launcher ----------------
extern "C" void kernel_launch(void* const* d_in, const int* in_sizes, int n_in,
                              void* d_out, int out_size, void* d_ws, size_t ws_size,
                              hipStream_t stream) {
  (void)in_sizes; (void)n_in; (void)out_size; (void)ws_size;
  const float* x    = (const float*)d_in[0];
  const int*   am   = (const int*)d_in[1];
  const float* qkvw = (const float*)d_in[2];
  const float* qkvb = (const float*)d_in[3];
  const float* qw   = (const float*)d_in[4];
  const float* qb   = (const float*)d_in[5];
  const float* kw   = (const float*)d_in[6];
  const float* kb   = (const float*)d_in[7];
  const float* vw   = (const float*)d_in[8];
  const float* vb   = (const float*)d_in[9];
  const float* ow   = (const float*)d_in[10];
  const float* ob   = (const float*)d_in[11];

  char* p = (char*)d_ws;
  auto take = [&](size_t n) { char* r = p; p += (n + 255) & ~(size_t)255; return r; };
  u16* xb    = (u16*)take(8192ull * 1024 * 2);        // also reused as attention output
  u16* qkvwT = (u16*)take(1024ull * 3072 * 2);
  u16* wb4   = (u16*)take(4ull * 1048576 * 2);        // qwb,kwb,vwb,owb
  u16* comb3 = (u16*)take(3ull * 1048576 * 2);        // comb_q (pre-scaled), comb_k, comb_v
  float* cb3 = (float*)take(3ull * 1024 * 4);
  u16* QK2   = (u16*)take(8192ull * 2048 * 2);        // fused [Q|K] (8192 x 2048)
  u16* V2t   = (u16*)take(8192ull * 1024 * 2);
  u64* pm    = (u64*)take(2048ull * 32 * 8);
  u16* Obuf  = xb;                                    // alias: xb dead after projections

  cvt_f32_bf16<<<8192, 256, 0, stream>>>(x, xb, 8192 * 1024);
  cvt4<<<dim3(1024, 4), 256, 0, stream>>>(qw, kw, vw, ow, wb4);
  transpose_f32_bf16<<<dim3(32, 96), 256, 0, stream>>>(qkvw, qkvwT, 3072, 1024);
  cbias3<<<dim3(256, 3), 256, 0, stream>>>(qw, kw, vw, qkvb, qb, kb, vb, cb3);

  // combined weights: comb_z[o][i] = sum_m W_z[o][m] * qkv_w[z*1024+m][i]; z==0 scaled
  gemm_nt<u16, false><<<dim3(64, 1, 3), 256, 0, stream>>>(
      wb4, 1024, 1048576, qkvwT, 3072, 1024, comb3, 1024, 1048576, nullptr, 0, 8, 1024, kQScale);
  // fused Q|K projection: C[8192][2048] = xb @ [comb_q; comb_k]^T + [cb_q; cb_k]
  gemm256<<<256, 512, 0, stream>>>(xb, 1024, comb3, 1024, QK2, 2048, cb3, 1024, 8);
  // V transposed: V2t[o][t] = comb_v[o]·x[t] + cb_v[o]  (bias per row)
  gemm_nt<u16, true><<<dim3(512, 1, 1), 256, 0, stream>>>(
      comb3 + 2 * 1048576, 1024, 0, xb, 1024, 0, V2t, 8192, 0, cb3 + 2048, 0, 64, 1024, 1.f);

  pack_mask<<<2048, 256, 0, stream>>>(am, pm);
  attn_fwd<<<512, 256, 0, stream>>>(QK2, QK2 + 1024, 2048, V2t, pm, Obuf);

  // out = O @ out_w^T + out_b  (fp32 output)
  gemm_nt<float, false><<<dim3(512, 1, 1), 256, 0, stream>>>(
      Obuf, 1024, 0, wb4 + 3 * 1048576, 1024, 0, (float*)d_out, 1024, 0, ob, 0, 8, 1024, 1.f);
}